// Round 11
// baseline (238.465 us; speedup 1.0000x reference)
//
#include <hip/hip_runtime.h>

#define D 128
#define WS (D + 8)      // LDS row stride in f16: 68 words -> 8-round b128 reads (optimal)
#define NEG_SLOPE 0.2f
#define SLOTS 20        // fixed CSR slots per node; P(deg>20)~3e-5 -> overflow list
#define OVF_CAP 4096

using v8f16 = __attribute__((ext_vector_type(8))) _Float16;
using v2h   = __attribute__((ext_vector_type(2))) _Float16;
using f32x4 = __attribute__((ext_vector_type(4))) float;

// ---------------- prep: zero cnt, init csr slots 0..7 to owning node, convert W1/W2 ----------
// Only the first 8 slots need node-init: the aggregate's speculative trip-0
// reads slots 0..7 unguarded; trips >=1 are cnt-guarded. Rank overwrites
// slots 0..deg-1 deterministically.

__global__ __launch_bounds__(256) void prep_kernel(const float* __restrict__ W1,
        const float* __restrict__ W2, _Float16* __restrict__ Wt1,
        _Float16* __restrict__ Wt2, int* __restrict__ cnt, int* __restrict__ csr,
        int* __restrict__ ovf_n, int n) {
    int t = blockIdx.x * 256 + threadIdx.x;   // 0..32767
    if (t == 0) *ovf_n = 0;
    for (int i = t; i < n; i += 32768) {
        cnt[i] = 0;
        #pragma unroll
        for (int j = 0; j < 8; ++j) csr[i * SLOTS + j] = i;
    }
    int which = t >> 14;
    int idx = t & 16383;
    int k = idx & (D - 1);
    int c = idx >> 7;
    const float* W = which ? W2 : W1;
    _Float16* Wt = which ? Wt2 : Wt1;
    Wt[(size_t)c * D + k] = (_Float16)W[(size_t)k * D + c];
}

// ---------------- GEMM body (LDS-staged W via ds_write, padded; 2 tiles/block) -------------

// H[n x 128](f16) = X @ W via mfma_f32_16x16x32_f16. 8 waves per block share
// ONE 32KB W stage, amortized over TWO 128-row tile passes (256 rows/block).
// Row stride WS=D+8 gives the proven 8-round b128 LDS read pattern (the 800K
// counted "conflicts" are this hardware-floor multi-round pattern -- benign).
// R7 trap + fix: a plain 2-tile loop software-pipelines across tiles and
// blows VGPR 52->108 (occupancy halves). __builtin_amdgcn_sched_barrier(0)
// between tiles pins strict serialization so per-tile register lifetimes
// don't overlap -- VGPR must stay <=64 (CHECK THE COUNTER; >64 = revert).
// R2: W must come from LDS. R4: non-swapped MFMA. R6: per-t 32B H stores
// merge in L2. R9: keep ds_write staging (global_load_lds drain regresses).
// Fused epilogue from fp32 accumulators: hs = H·a_src, hd = H·a_dst.
template<bool F16IN>
__device__ __forceinline__ void gemm_body(int bid, const void* __restrict__ Xv,
        const _Float16* __restrict__ Wt, const float* __restrict__ a_src,
        const float* __restrict__ a_dst, _Float16* __restrict__ H,
        float* __restrict__ hs, float* __restrict__ hd, int n,
        _Float16* wl) {
    const int lane = threadIdx.x & 63;
    const int wave = threadIdx.x >> 6;           // 0..7
    const int gl = lane & 15;
    const int q = lane >> 4;

    // stage W into LDS once: 128 rows x 128 f16, 16 chunks of 8 f16 per row
    for (int i = threadIdx.x; i < D * D / 8; i += 512) {
        int r = i >> 4;
        int c = (i & 15) * 8;
        *(v8f16*)&wl[r * WS + c] = *(const v8f16*)&Wt[r * D + c];
    }
    __syncthreads();

    #pragma unroll 1
    for (int tile = 0; tile < 2; ++tile) {
        const int row0 = bid * 256 + tile * 128 + wave * 16;

        int arow = row0 + gl;
        if (arow >= n) arow = n - 1;   // clamped load; stores are guarded below

        v8f16 afr[4];
        #pragma unroll
        for (int kc = 0; kc < 4; ++kc) {
            if constexpr (F16IN) {
                const _Float16* Xh = (const _Float16*)Xv;
                afr[kc] = *(const v8f16*)&Xh[(size_t)arow * D + kc * 32 + q * 8];
            } else {
                const float* p = &((const float*)Xv)[(size_t)arow * D + kc * 32 + q * 8];
                float4 x0 = *(const float4*)p;
                float4 x1 = *(const float4*)(p + 4);
                v8f16 t;
                t[0] = (_Float16)x0.x; t[1] = (_Float16)x0.y;
                t[2] = (_Float16)x0.z; t[3] = (_Float16)x0.w;
                t[4] = (_Float16)x1.x; t[5] = (_Float16)x1.y;
                t[6] = (_Float16)x1.z; t[7] = (_Float16)x1.w;
                afr[kc] = t;
            }
        }

        f32x4 acc[8];
        #pragma unroll
        for (int t = 0; t < 8; ++t) acc[t] = (f32x4){0.f, 0.f, 0.f, 0.f};

        #pragma unroll
        for (int kc = 0; kc < 4; ++kc) {
            #pragma unroll
            for (int t = 0; t < 8; ++t) {
                v8f16 bfr = *(const v8f16*)&wl[(t * 16 + gl) * WS + kc * 32 + q * 8];
                acc[t] = __builtin_amdgcn_mfma_f32_16x16x32_f16(afr[kc], bfr, acc[t], 0, 0, 0);
            }
        }

        float asv[8], adv[8];
        #pragma unroll
        for (int t = 0; t < 8; ++t) { asv[t] = a_src[t * 16 + gl]; adv[t] = a_dst[t * 16 + gl]; }

        // C/D layout: col = t*16 + (lane&15), row = row0 + q*4 + reg
        #pragma unroll
        for (int r = 0; r < 4; ++r) {
            int row = row0 + q * 4 + r;
            bool ok = row < n;
            float ps = 0.f, pd = 0.f;
            #pragma unroll
            for (int t = 0; t < 8; ++t) {
                float v = acc[t][r];
                ps = fmaf(v, asv[t], ps);
                pd = fmaf(v, adv[t], pd);
                if (ok) H[(size_t)row * D + t * 16 + gl] = (_Float16)v;
            }
            #pragma unroll
            for (int dlt = 8; dlt > 0; dlt >>= 1) {
                ps += __shfl_down(ps, dlt, 16);
                pd += __shfl_down(pd, dlt, 16);
            }
            if (ok && gl == 0) { hs[row] = ps; hd[row] = pd; }
        }

        // pin strict tile serialization: no cross-tile register overlap (R7 fix)
        __builtin_amdgcn_sched_barrier(0);
    }
}

// ---------------- mega1: GEMM1 interleaved with rank-to-fixed-slot CSR ----------------
// Blocks < 2*eb alternate GEMM/rank; blocks >= 2*eb are GEMM, so both
// populations are co-resident from t=0 (requires eb <= gb: 355 <= 391 ok).
// R11: rank threads handle FOUR edges each (R8/R9 ILP recipe, deepened):
// all 4 ei loads, 4 atomics, 4 csr stores issue as independent chains.

__global__ __launch_bounds__(512) void mega1_kernel(
        const float* __restrict__ x, const _Float16* __restrict__ Wt1,
        const float* __restrict__ a_src1, const float* __restrict__ a_dst1,
        _Float16* __restrict__ h, float* __restrict__ hs, float* __restrict__ hd,
        const int* __restrict__ ei, int* __restrict__ cnt, int* __restrict__ csr,
        int* __restrict__ ovf_n, int* __restrict__ ovf,
        int eb, int e_in, int n) {
    __shared__ _Float16 wl[D * WS];
    int b = blockIdx.x;
    int rid;
    if (b < 2 * eb) {
        if ((b & 1) == 0) {
            gemm_body<false>(b >> 1, x, Wt1, a_src1, a_dst1, h, hs, hd, n, wl);
            return;
        }
        rid = b >> 1;
    } else {
        gemm_body<false>(b - eb, x, Wt1, a_src1, a_dst1, h, hs, hd, n, wl);
        return;
    }
    int tot = e_in + n;
    int e0 = rid * 2048 + threadIdx.x;
    int es[4] = {e0, e0 + 512, e0 + 1024, e0 + 1536};
    int sv[4], dv[4], rv[4];
    bool vv[4];
    #pragma unroll
    for (int k = 0; k < 4; ++k) {
        int e = es[k];
        vv[k] = e < tot;
        sv[k] = 0; dv[k] = 0;
        if (vv[k]) {
            if (e < e_in) { sv[k] = ei[e]; dv[k] = ei[e_in + e]; }
            else          { sv[k] = e - e_in; dv[k] = sv[k]; }
        }
    }
    #pragma unroll
    for (int k = 0; k < 4; ++k)
        rv[k] = vv[k] ? atomicAdd(&cnt[dv[k]], 1) : 0;
    #pragma unroll
    for (int k = 0; k < 4; ++k) {
        if (vv[k]) {
            if (rv[k] < SLOTS) csr[dv[k] * SLOTS + rv[k]] = sv[k];
            else {
                int ix = atomicAdd(ovf_n, 1);
                if (ix < OVF_CAP) { ovf[2 * ix] = dv[k]; ovf[2 * ix + 1] = sv[k]; }
            }
        }
    }
}

__global__ __launch_bounds__(512) void gemm2_kernel(
        const _Float16* __restrict__ tb, const _Float16* __restrict__ Wt2,
        const float* __restrict__ a_src2, const float* __restrict__ a_dst2,
        _Float16* __restrict__ h, float* __restrict__ hs, float* __restrict__ hd,
        int n) {
    __shared__ _Float16 wl[D * WS];
    gemm_body<true>(blockIdx.x, tb, Wt2, a_src2, a_dst2, h, hs, hd, n, wl);
}

// ---------------- aggregate (unchanged from R8 -- proven) ----------------

__device__ __forceinline__ v2h pack_lo(uint a, uint b) {
    v2h r;
    r.x = __builtin_bit_cast(_Float16, (unsigned short)(a & 0xffffu));
    r.y = __builtin_bit_cast(_Float16, (unsigned short)(b & 0xffffu));
    return r;
}
__device__ __forceinline__ v2h pack_hi(uint a, uint b) {
    v2h r;
    r.x = __builtin_bit_cast(_Float16, (unsigned short)(a >> 16));
    r.y = __builtin_bit_cast(_Float16, (unsigned short)(b >> 16));
    return r;
}
__device__ __forceinline__ float lo_f(uint a) {
    return (float)__builtin_bit_cast(_Float16, (unsigned short)(a & 0xffffu));
}
__device__ __forceinline__ float hi_f(uint a) {
    return (float)__builtin_bit_cast(_Float16, (unsigned short)(a >> 16));
}

// helper: one fdot2 accumulation round (2 slots' rows into acc)
__device__ __forceinline__ void acc_pair(float* acc, const uint4& rA,
        const uint4& rB, float w0, float w1) {
#if __has_builtin(__builtin_amdgcn_fdot2)
    v2h wp; wp.x = (_Float16)w0; wp.y = (_Float16)w1;
    acc[0] = __builtin_amdgcn_fdot2(pack_lo(rA.x, rB.x), wp, acc[0], false);
    acc[1] = __builtin_amdgcn_fdot2(pack_hi(rA.x, rB.x), wp, acc[1], false);
    acc[2] = __builtin_amdgcn_fdot2(pack_lo(rA.y, rB.y), wp, acc[2], false);
    acc[3] = __builtin_amdgcn_fdot2(pack_hi(rA.y, rB.y), wp, acc[3], false);
    acc[4] = __builtin_amdgcn_fdot2(pack_lo(rA.z, rB.z), wp, acc[4], false);
    acc[5] = __builtin_amdgcn_fdot2(pack_hi(rA.z, rB.z), wp, acc[5], false);
    acc[6] = __builtin_amdgcn_fdot2(pack_lo(rA.w, rB.w), wp, acc[6], false);
    acc[7] = __builtin_amdgcn_fdot2(pack_hi(rA.w, rB.w), wp, acc[7], false);
#else
    acc[0] = fmaf(w0, lo_f(rA.x), acc[0]); acc[1] = fmaf(w0, hi_f(rA.x), acc[1]);
    acc[2] = fmaf(w0, lo_f(rA.y), acc[2]); acc[3] = fmaf(w0, hi_f(rA.y), acc[3]);
    acc[4] = fmaf(w0, lo_f(rA.z), acc[4]); acc[5] = fmaf(w0, hi_f(rA.z), acc[5]);
    acc[6] = fmaf(w0, lo_f(rA.w), acc[6]); acc[7] = fmaf(w0, hi_f(rA.w), acc[7]);
    acc[0] = fmaf(w1, lo_f(rB.x), acc[0]); acc[1] = fmaf(w1, hi_f(rB.x), acc[1]);
    acc[2] = fmaf(w1, lo_f(rB.y), acc[2]); acc[3] = fmaf(w1, hi_f(rB.y), acc[3]);
    acc[4] = fmaf(w1, lo_f(rB.z), acc[4]); acc[5] = fmaf(w1, hi_f(rB.z), acc[5]);
    acc[6] = fmaf(w1, lo_f(rB.w), acc[6]); acc[7] = fmaf(w1, hi_f(rB.w), acc[7]);
#endif
}

// TWO nodes per wave (ILP-stacking), 8 nodes per 256-thread block. Per node,
// group grp (lane>>4) handles slot pairs (8u+2*grp, 8u+2*grp+1). TRIP 0 IS
// SPECULATIVE for BOTH nodes: cnt/hd/csr(0..7) for A and B issue concurrently
// (depend only on node id), then all 4 row-gathers + hs -- ~20 loads in
// flight per wave, 2x the old MLP at the same occupancy (VGPR ~56 < 64 step).
// Validity masks (needing cnt) apply to WEIGHTS only; slots 0..7 >= deg hold
// the node id (prep-initialized), bounds clamp as insurance. Guarded trips
// 1..2 and overflow handled per-node (31%/1%/rare).
template<bool OUT_F16>
__global__ __launch_bounds__(256) void aggregate_kernel(
        const _Float16* __restrict__ h, const float* __restrict__ hs,
        const float* __restrict__ hd, const int* __restrict__ cnt,
        const int* __restrict__ csr, const int* __restrict__ ovf_n,
        const int* __restrict__ ovf, const float* __restrict__ bias,
        float* __restrict__ outf, _Float16* __restrict__ outb, int n) {
    int nodeA = (blockIdx.x * 4 + (threadIdx.x >> 6)) * 2;
    if (nodeA >= n) return;
    int nodeB = nodeA + 1;
    bool hasB = nodeB < n;
    int nBs = hasB ? nodeB : nodeA;       // safe id for B-side loads
    int lane = threadIdx.x & 63;
    int grp = lane >> 4;
    int gl = lane & 15;
    const int baseA = nodeA * SLOTS;
    const int baseB = nBs * SLOTS;
    const uint* hp = (const uint*)h;   // 2 f16 per uint, row stride 64 uints

    // --- speculative trip 0 for BOTH nodes: everything below issues before cnt returns ---
    int degA = cnt[nodeA];
    int degB = cnt[nBs];
    float hdA = hd[nodeA];
    float hdB = hd[nBs];
    int jb = grp * 2;
    int cA0 = csr[baseA + jb];
    int cA1 = csr[baseA + jb + 1];
    int cB0 = csr[baseB + jb];
    int cB1 = csr[baseB + jb + 1];
    int sA0 = ((uint)cA0 < (uint)n) ? cA0 : nodeA;   // safety clamp (cheap)
    int sA1 = ((uint)cA1 < (uint)n) ? cA1 : nodeA;
    int sB0 = ((uint)cB0 < (uint)n) ? cB0 : nBs;
    int sB1 = ((uint)cB1 < (uint)n) ? cB1 : nBs;
    uint4 rA0 = *(const uint4*)(hp + ((size_t)sA0 << 6) + (gl << 2));
    uint4 rA1 = *(const uint4*)(hp + ((size_t)sA1 << 6) + (gl << 2));
    uint4 rB0 = *(const uint4*)(hp + ((size_t)sB0 << 6) + (gl << 2));
    uint4 rB1 = *(const uint4*)(hp + ((size_t)sB1 << 6) + (gl << 2));
    float eA0 = hs[sA0] + hdA;
    float eA1 = hs[sA1] + hdA;
    float eB0 = hs[sB0] + hdB;
    float eB1 = hs[sB1] + hdB;

    float accA[8] = {0.f, 0.f, 0.f, 0.f, 0.f, 0.f, 0.f, 0.f};
    float accB[8] = {0.f, 0.f, 0.f, 0.f, 0.f, 0.f, 0.f, 0.f};
    float zA = 0.f, zB = 0.f;

    int mindA = degA < SLOTS ? degA : SLOTS;
    int mindB = degB < SLOTS ? degB : SLOTS;
    eA0 = eA0 > 0.f ? eA0 : NEG_SLOPE * eA0;
    eA1 = eA1 > 0.f ? eA1 : NEG_SLOPE * eA1;
    eB0 = eB0 > 0.f ? eB0 : NEG_SLOPE * eB0;
    eB1 = eB1 > 0.f ? eB1 : NEG_SLOPE * eB1;
    float wA0 = (jb < mindA) ? __expf(eA0) : 0.f;
    float wA1 = (jb + 1 < mindA) ? __expf(eA1) : 0.f;
    float wB0 = (jb < mindB) ? __expf(eB0) : 0.f;
    float wB1 = (jb + 1 < mindB) ? __expf(eB1) : 0.f;
    zA += wA0 + wA1;
    zB += wB0 + wB1;
    acc_pair(accA, rA0, rA1, wA0, wA1);
    acc_pair(accB, rB0, rB1, wB0, wB1);

    // --- guarded trips 1..nt-1, per node (31% take trip 1, ~1% trip 2) ---
    int ntA = (mindA + 7) >> 3;
    for (int u = 1; u < ntA; ++u) {
        int i0 = u * 8 + jb;
        bool a0 = i0 < mindA;
        bool a1 = i0 + 1 < mindA;
        int t0 = a0 ? csr[baseA + i0] : nodeA;
        int t1 = a1 ? csr[baseA + i0 + 1] : nodeA;
        uint4 qA = *(const uint4*)(hp + ((size_t)t0 << 6) + (gl << 2));
        uint4 qB = *(const uint4*)(hp + ((size_t)t1 << 6) + (gl << 2));
        float f0 = hs[t0] + hdA;
        f0 = f0 > 0.f ? f0 : NEG_SLOPE * f0;
        float f1 = hs[t1] + hdA;
        f1 = f1 > 0.f ? f1 : NEG_SLOPE * f1;
        float v0 = a0 ? __expf(f0) : 0.f;
        float v1 = a1 ? __expf(f1) : 0.f;
        zA += v0 + v1;
        acc_pair(accA, qA, qB, v0, v1);
    }
    int ntB = (mindB + 7) >> 3;
    for (int u = 1; u < ntB; ++u) {
        int i0 = u * 8 + jb;
        bool a0 = i0 < mindB;
        bool a1 = i0 + 1 < mindB;
        int t0 = a0 ? csr[baseB + i0] : nBs;
        int t1 = a1 ? csr[baseB + i0 + 1] : nBs;
        uint4 qA = *(const uint4*)(hp + ((size_t)t0 << 6) + (gl << 2));
        uint4 qB = *(const uint4*)(hp + ((size_t)t1 << 6) + (gl << 2));
        float f0 = hs[t0] + hdB;
        f0 = f0 > 0.f ? f0 : NEG_SLOPE * f0;
        float f1 = hs[t1] + hdB;
        f1 = f1 > 0.f ? f1 : NEG_SLOPE * f1;
        float v0 = a0 ? __expf(f0) : 0.f;
        float v1 = a1 ? __expf(f1) : 0.f;
        zB += v0 + v1;
        acc_pair(accB, qA, qB, v0, v1);
    }

    // rare: overflow list scan, per node
    if (degA > SLOTS || degB > SLOTS) {
        int m = *ovf_n;
        if (m > OVF_CAP) m = OVF_CAP;
        for (int i = 0; i < m; ++i) {
            int od = ovf[2 * i];
            if (od == nodeA || (hasB && od == nodeB)) {
                bool isA = (od == nodeA);
                int os = ovf[2 * i + 1];
                float e = hs[os] + (isA ? hdA : hdB);
                e = e > 0.f ? e : NEG_SLOPE * e;
                float wv = __expf(e);
                if (grp == 0) {
                    uint4 rr = *(const uint4*)(hp + ((size_t)os << 6) + (gl << 2));
                    float* ac = isA ? accA : accB;
                    ac[0] = fmaf(wv, lo_f(rr.x), ac[0]); ac[1] = fmaf(wv, hi_f(rr.x), ac[1]);
                    ac[2] = fmaf(wv, lo_f(rr.y), ac[2]); ac[3] = fmaf(wv, hi_f(rr.y), ac[3]);
                    ac[4] = fmaf(wv, lo_f(rr.z), ac[4]); ac[5] = fmaf(wv, hi_f(rr.z), ac[5]);
                    ac[6] = fmaf(wv, lo_f(rr.w), ac[6]); ac[7] = fmaf(wv, hi_f(rr.w), ac[7]);
                    if (isA) zA += wv; else zB += wv;
                }
            }
        }
    }

    // combine the 4 slot groups -> lanes 0..15 hold both full rows
    #pragma unroll
    for (int dlt = 32; dlt >= 16; dlt >>= 1) {
        #pragma unroll
        for (int k = 0; k < 8; ++k) {
            accA[k] += __shfl_down(accA[k], dlt, 64);
            accB[k] += __shfl_down(accB[k], dlt, 64);
        }
        zA += __shfl_down(zA, dlt, 64);
        zB += __shfl_down(zB, dlt, 64);
    }
    if (lane < 16) {
        float4 b0 = *(const float4*)&bias[lane * 8];
        float4 b1 = *(const float4*)&bias[lane * 8 + 4];
        float invA = 1.0f / zA;   // self-loop guarantees z > 0
        float oA[8];
        oA[0] = accA[0] * invA + b0.x; oA[1] = accA[1] * invA + b0.y;
        oA[2] = accA[2] * invA + b0.z; oA[3] = accA[3] * invA + b0.w;
        oA[4] = accA[4] * invA + b1.x; oA[5] = accA[5] * invA + b1.y;
        oA[6] = accA[6] * invA + b1.z; oA[7] = accA[7] * invA + b1.w;
        #pragma unroll
        for (int k = 0; k < 8; ++k) oA[k] = oA[k] > 0.f ? oA[k] : 0.f;
        if constexpr (OUT_F16) {
            alignas(16) _Float16 ob[8];
            #pragma unroll
            for (int k = 0; k < 8; ++k) ob[k] = (_Float16)oA[k];
            *(uint4*)&outb[(size_t)nodeA * D + lane * 8] = *(const uint4*)ob;
        } else {
            float* op = outf + (size_t)nodeA * D + lane * 8;
            *(float4*)op = make_float4(oA[0], oA[1], oA[2], oA[3]);
            *(float4*)(op + 4) = make_float4(oA[4], oA[5], oA[6], oA[7]);
        }
        if (hasB) {
            float invB = 1.0f / zB;
            float oB[8];
            oB[0] = accB[0] * invB + b0.x; oB[1] = accB[1] * invB + b0.y;
            oB[2] = accB[2] * invB + b0.z; oB[3] = accB[3] * invB + b0.w;
            oB[4] = accB[4] * invB + b1.x; oB[5] = accB[5] * invB + b1.y;
            oB[6] = accB[6] * invB + b1.z; oB[7] = accB[7] * invB + b1.w;
            #pragma unroll
            for (int k = 0; k < 8; ++k) oB[k] = oB[k] > 0.f ? oB[k] : 0.f;
            if constexpr (OUT_F16) {
                alignas(16) _Float16 ob[8];
                #pragma unroll
                for (int k = 0; k < 8; ++k) ob[k] = (_Float16)oB[k];
                *(uint4*)&outb[(size_t)nodeB * D + lane * 8] = *(const uint4*)ob;
            } else {
                float* op = outf + (size_t)nodeB * D + lane * 8;
                *(float4*)op = make_float4(oB[0], oB[1], oB[2], oB[3]);
                *(float4*)(op + 4) = make_float4(oB[4], oB[5], oB[6], oB[7]);
            }
        }
    }
}

// ---------------- Orchestration ----------------

extern "C" void kernel_launch(void* const* d_in, const int* in_sizes, int n_in,
                              void* d_out, int out_size, void* d_ws, size_t ws_size,
                              hipStream_t stream) {
    const float* x      = (const float*)d_in[0];
    const int*   ei     = (const int*)d_in[1];
    const float* W1     = (const float*)d_in[2];
    const float* a_src1 = (const float*)d_in[3];
    const float* a_dst1 = (const float*)d_in[4];
    const float* b1     = (const float*)d_in[5];
    const float* W2     = (const float*)d_in[6];
    const float* a_src2 = (const float*)d_in[7];
    const float* a_dst2 = (const float*)d_in[8];
    const float* b2     = (const float*)d_in[9];

    int n    = in_sizes[0] / D;       // 100000
    int e_in = in_sizes[1] / 2;       // 625000
    int e_tot = e_in + n;             // 725000

    // ws: h(f16) | Wt1 | Wt2 | hs | hd | cnt | ovf_n | ovf | csr  (~33 MB)
    _Float16* h   = (_Float16*)d_ws;
    _Float16* Wt1 = h + (size_t)n * D;
    _Float16* Wt2 = Wt1 + D * D;
    float* hs     = (float*)(Wt2 + D * D);
    float* hd     = hs + n;
    int*   cnt    = (int*)(hd + n);
    int*   ovf_n  = cnt + n;
    int*   ovf    = ovf_n + 1;
    int*   csr    = ovf + 2 * OVF_CAP;
    // layer-1 f16 output lives in d_out's first half (dead before agg2's fp32 write)
    _Float16* tb  = (_Float16*)d_out;

    int eb = (e_tot + 2047) / 2048;   // 355 rank blocks (4 edges/thread)
    int nb8 = (n + 7) / 8;            // 12500 (8 nodes per 256-thread block)
    int gb = (n + 255) / 256;         // 391 GEMM blocks (2 tiles each; eb <= gb ok)

    prep_kernel<<<128, 256, 0, stream>>>(W1, W2, Wt1, Wt2, cnt, csr, ovf_n, n);
    mega1_kernel<<<gb + eb, 512, 0, stream>>>(x, Wt1, a_src1, a_dst1, h, hs, hd,
                                              ei, cnt, csr, ovf_n, ovf, eb, e_in, n);
    aggregate_kernel<true><<<nb8, 256, 0, stream>>>(h, hs, hd, cnt, csr, ovf_n, ovf,
                                                    b1, nullptr, tb, n);
    gemm2_kernel<<<gb, 512, 0, stream>>>(tb, Wt2, a_src2, a_dst2, h, hs, hd, n);
    aggregate_kernel<false><<<nb8, 256, 0, stream>>>(h, hs, hd, cnt, csr, ovf_n, ovf,
                                                     b2, (float*)d_out, nullptr, n);
}

// Round 12
// 232.700 us; speedup vs baseline: 1.0248x; 1.0248x over previous
//
#include <hip/hip_runtime.h>

#define D 128
#define WS (D + 8)      // LDS row stride in f16: 68 words -> 8-round b128 reads (optimal)
#define NEG_SLOPE 0.2f
#define SLOTS 20        // fixed CSR slots per node; P(deg>20)~3e-5 -> overflow list
#define OVF_CAP 4096

using v8f16 = __attribute__((ext_vector_type(8))) _Float16;
using v2h   = __attribute__((ext_vector_type(2))) _Float16;
using f32x4 = __attribute__((ext_vector_type(4))) float;

// ---------------- prep: zero cnt, init csr slots 0..7 to owning node, convert W1/W2 ----------
// Only the first 8 slots need node-init: the aggregate's speculative trip-0
// reads slots 0..7 unguarded; trips >=1 are cnt-guarded. Rank overwrites
// slots 0..deg-1 deterministically.

__global__ __launch_bounds__(256) void prep_kernel(const float* __restrict__ W1,
        const float* __restrict__ W2, _Float16* __restrict__ Wt1,
        _Float16* __restrict__ Wt2, int* __restrict__ cnt, int* __restrict__ csr,
        int* __restrict__ ovf_n, int n) {
    int t = blockIdx.x * 256 + threadIdx.x;   // 0..32767
    if (t == 0) *ovf_n = 0;
    for (int i = t; i < n; i += 32768) {
        cnt[i] = 0;
        #pragma unroll
        for (int j = 0; j < 8; ++j) csr[i * SLOTS + j] = i;
    }
    int which = t >> 14;
    int idx = t & 16383;
    int k = idx & (D - 1);
    int c = idx >> 7;
    const float* W = which ? W2 : W1;
    _Float16* Wt = which ? Wt2 : Wt1;
    Wt[(size_t)c * D + k] = (_Float16)W[(size_t)k * D + c];
}

// ---------------- GEMM body (R10-proven: LDS-staged W via ds_write, padded, 128-row) --------

// H[n x 128](f16) = X @ W via mfma_f32_16x16x32_f16. 8 waves per block share
// ONE 32KB W stage (128 rows each block). Row stride WS=D+8 gives the proven
// 8-round b128 LDS read pattern (the 800K counted "conflicts" are this
// hardware-floor multi-round pattern -- benign, read-side, R9-verified).
// R2: W must come from LDS. R4: non-swapped MFMA. R6: per-t 32B H stores
// merge in L2. R7+R11: do NOT grow the tile (VGPR blowup / grid
// under-subscription: 782-block 128-row 52-VGPR is the measured optimum).
// R9: keep ds_write staging (global_load_lds drain regresses pure-GEMM).
// Fused epilogue from fp32 accumulators: hs = H·a_src, hd = H·a_dst.
template<bool F16IN>
__device__ __forceinline__ void gemm_body(int bid, const void* __restrict__ Xv,
        const _Float16* __restrict__ Wt, const float* __restrict__ a_src,
        const float* __restrict__ a_dst, _Float16* __restrict__ H,
        float* __restrict__ hs, float* __restrict__ hd, int n,
        _Float16* wl) {
    const int lane = threadIdx.x & 63;
    const int wave = threadIdx.x >> 6;           // 0..7
    const int gl = lane & 15;
    const int q = lane >> 4;
    const int row0 = bid * 128 + wave * 16;

    int arow = row0 + gl;
    if (arow >= n) arow = n - 1;   // clamped load; stores are guarded below

    // A fragments first (independent of LDS staging)
    v8f16 afr[4];
    #pragma unroll
    for (int kc = 0; kc < 4; ++kc) {
        if constexpr (F16IN) {
            const _Float16* Xh = (const _Float16*)Xv;
            afr[kc] = *(const v8f16*)&Xh[(size_t)arow * D + kc * 32 + q * 8];
        } else {
            const float* p = &((const float*)Xv)[(size_t)arow * D + kc * 32 + q * 8];
            float4 x0 = *(const float4*)p;
            float4 x1 = *(const float4*)(p + 4);
            v8f16 t;
            t[0] = (_Float16)x0.x; t[1] = (_Float16)x0.y;
            t[2] = (_Float16)x0.z; t[3] = (_Float16)x0.w;
            t[4] = (_Float16)x1.x; t[5] = (_Float16)x1.y;
            t[6] = (_Float16)x1.z; t[7] = (_Float16)x1.w;
            afr[kc] = t;
        }
    }

    // stage W into LDS: 128 rows x 128 f16, 16 chunks of 8 f16 per row
    for (int i = threadIdx.x; i < D * D / 8; i += 512) {
        int r = i >> 4;
        int c = (i & 15) * 8;
        *(v8f16*)&wl[r * WS + c] = *(const v8f16*)&Wt[r * D + c];
    }
    __syncthreads();

    f32x4 acc[8];
    #pragma unroll
    for (int t = 0; t < 8; ++t) acc[t] = (f32x4){0.f, 0.f, 0.f, 0.f};

    #pragma unroll
    for (int kc = 0; kc < 4; ++kc) {
        #pragma unroll
        for (int t = 0; t < 8; ++t) {
            v8f16 bfr = *(const v8f16*)&wl[(t * 16 + gl) * WS + kc * 32 + q * 8];
            acc[t] = __builtin_amdgcn_mfma_f32_16x16x32_f16(afr[kc], bfr, acc[t], 0, 0, 0);
        }
    }

    float asv[8], adv[8];
    #pragma unroll
    for (int t = 0; t < 8; ++t) { asv[t] = a_src[t * 16 + gl]; adv[t] = a_dst[t * 16 + gl]; }

    // C/D layout: col = t*16 + (lane&15), row = row0 + q*4 + reg
    #pragma unroll
    for (int r = 0; r < 4; ++r) {
        int row = row0 + q * 4 + r;
        bool ok = row < n;
        float ps = 0.f, pd = 0.f;
        #pragma unroll
        for (int t = 0; t < 8; ++t) {
            float v = acc[t][r];
            ps = fmaf(v, asv[t], ps);
            pd = fmaf(v, adv[t], pd);
            if (ok) H[(size_t)row * D + t * 16 + gl] = (_Float16)v;
        }
        #pragma unroll
        for (int dlt = 8; dlt > 0; dlt >>= 1) {
            ps += __shfl_down(ps, dlt, 16);
            pd += __shfl_down(pd, dlt, 16);
        }
        if (ok && gl == 0) { hs[row] = ps; hd[row] = pd; }
    }
}

// ---------------- mega1: GEMM1 interleaved with rank-to-fixed-slot CSR ----------------
// Blocks < 2*eb alternate GEMM/rank; blocks >= 2*eb are GEMM, so both
// populations are co-resident from t=0 (requires eb <= gb: 355 <= 782 ok).
// R12: rank threads handle FOUR edges each (deepened R9/R10 ILP recipe):
// all 4 ei loads, 4 atomics, 4 csr stores issue as independent chains.
// GEMM body and grid (782 x 128-row) byte-identical to R10's proven best.

__global__ __launch_bounds__(512) void mega1_kernel(
        const float* __restrict__ x, const _Float16* __restrict__ Wt1,
        const float* __restrict__ a_src1, const float* __restrict__ a_dst1,
        _Float16* __restrict__ h, float* __restrict__ hs, float* __restrict__ hd,
        const int* __restrict__ ei, int* __restrict__ cnt, int* __restrict__ csr,
        int* __restrict__ ovf_n, int* __restrict__ ovf,
        int eb, int e_in, int n) {
    __shared__ _Float16 wl[D * WS];
    int b = blockIdx.x;
    int rid;
    if (b < 2 * eb) {
        if ((b & 1) == 0) {
            gemm_body<false>(b >> 1, x, Wt1, a_src1, a_dst1, h, hs, hd, n, wl);
            return;
        }
        rid = b >> 1;
    } else {
        gemm_body<false>(b - eb, x, Wt1, a_src1, a_dst1, h, hs, hd, n, wl);
        return;
    }
    int tot = e_in + n;
    int e0 = rid * 2048 + threadIdx.x;
    int es[4] = {e0, e0 + 512, e0 + 1024, e0 + 1536};
    int sv[4], dv[4], rv[4];
    bool vv[4];
    #pragma unroll
    for (int k = 0; k < 4; ++k) {
        int e = es[k];
        vv[k] = e < tot;
        sv[k] = 0; dv[k] = 0;
        if (vv[k]) {
            if (e < e_in) { sv[k] = ei[e]; dv[k] = ei[e_in + e]; }
            else          { sv[k] = e - e_in; dv[k] = sv[k]; }
        }
    }
    #pragma unroll
    for (int k = 0; k < 4; ++k)
        rv[k] = vv[k] ? atomicAdd(&cnt[dv[k]], 1) : 0;
    #pragma unroll
    for (int k = 0; k < 4; ++k) {
        if (vv[k]) {
            if (rv[k] < SLOTS) csr[dv[k] * SLOTS + rv[k]] = sv[k];
            else {
                int ix = atomicAdd(ovf_n, 1);
                if (ix < OVF_CAP) { ovf[2 * ix] = dv[k]; ovf[2 * ix + 1] = sv[k]; }
            }
        }
    }
}

__global__ __launch_bounds__(512) void gemm2_kernel(
        const _Float16* __restrict__ tb, const _Float16* __restrict__ Wt2,
        const float* __restrict__ a_src2, const float* __restrict__ a_dst2,
        _Float16* __restrict__ h, float* __restrict__ hs, float* __restrict__ hd,
        int n) {
    __shared__ _Float16 wl[D * WS];
    gemm_body<true>(blockIdx.x, tb, Wt2, a_src2, a_dst2, h, hs, hd, n, wl);
}

// ---------------- aggregate (unchanged from R8 -- proven) ----------------

__device__ __forceinline__ v2h pack_lo(uint a, uint b) {
    v2h r;
    r.x = __builtin_bit_cast(_Float16, (unsigned short)(a & 0xffffu));
    r.y = __builtin_bit_cast(_Float16, (unsigned short)(b & 0xffffu));
    return r;
}
__device__ __forceinline__ v2h pack_hi(uint a, uint b) {
    v2h r;
    r.x = __builtin_bit_cast(_Float16, (unsigned short)(a >> 16));
    r.y = __builtin_bit_cast(_Float16, (unsigned short)(b >> 16));
    return r;
}
__device__ __forceinline__ float lo_f(uint a) {
    return (float)__builtin_bit_cast(_Float16, (unsigned short)(a & 0xffffu));
}
__device__ __forceinline__ float hi_f(uint a) {
    return (float)__builtin_bit_cast(_Float16, (unsigned short)(a >> 16));
}

// helper: one fdot2 accumulation round (2 slots' rows into acc)
__device__ __forceinline__ void acc_pair(float* acc, const uint4& rA,
        const uint4& rB, float w0, float w1) {
#if __has_builtin(__builtin_amdgcn_fdot2)
    v2h wp; wp.x = (_Float16)w0; wp.y = (_Float16)w1;
    acc[0] = __builtin_amdgcn_fdot2(pack_lo(rA.x, rB.x), wp, acc[0], false);
    acc[1] = __builtin_amdgcn_fdot2(pack_hi(rA.x, rB.x), wp, acc[1], false);
    acc[2] = __builtin_amdgcn_fdot2(pack_lo(rA.y, rB.y), wp, acc[2], false);
    acc[3] = __builtin_amdgcn_fdot2(pack_hi(rA.y, rB.y), wp, acc[3], false);
    acc[4] = __builtin_amdgcn_fdot2(pack_lo(rA.z, rB.z), wp, acc[4], false);
    acc[5] = __builtin_amdgcn_fdot2(pack_hi(rA.z, rB.z), wp, acc[5], false);
    acc[6] = __builtin_amdgcn_fdot2(pack_lo(rA.w, rB.w), wp, acc[6], false);
    acc[7] = __builtin_amdgcn_fdot2(pack_hi(rA.w, rB.w), wp, acc[7], false);
#else
    acc[0] = fmaf(w0, lo_f(rA.x), acc[0]); acc[1] = fmaf(w0, hi_f(rA.x), acc[1]);
    acc[2] = fmaf(w0, lo_f(rA.y), acc[2]); acc[3] = fmaf(w0, hi_f(rA.y), acc[3]);
    acc[4] = fmaf(w0, lo_f(rA.z), acc[4]); acc[5] = fmaf(w0, hi_f(rA.z), acc[5]);
    acc[6] = fmaf(w0, lo_f(rA.w), acc[6]); acc[7] = fmaf(w0, hi_f(rA.w), acc[7]);
    acc[0] = fmaf(w1, lo_f(rB.x), acc[0]); acc[1] = fmaf(w1, hi_f(rB.x), acc[1]);
    acc[2] = fmaf(w1, lo_f(rB.y), acc[2]); acc[3] = fmaf(w1, hi_f(rB.y), acc[3]);
    acc[4] = fmaf(w1, lo_f(rB.z), acc[4]); acc[5] = fmaf(w1, hi_f(rB.z), acc[5]);
    acc[6] = fmaf(w1, lo_f(rB.w), acc[6]); acc[7] = fmaf(w1, hi_f(rB.w), acc[7]);
#endif
}

// TWO nodes per wave (ILP-stacking), 8 nodes per 256-thread block. Per node,
// group grp (lane>>4) handles slot pairs (8u+2*grp, 8u+2*grp+1). TRIP 0 IS
// SPECULATIVE for BOTH nodes: cnt/hd/csr(0..7) for A and B issue concurrently
// (depend only on node id), then all 4 row-gathers + hs -- ~20 loads in
// flight per wave, 2x the old MLP at the same occupancy (VGPR ~56 < 64 step).
// Validity masks (needing cnt) apply to WEIGHTS only; slots 0..7 >= deg hold
// the node id (prep-initialized), bounds clamp as insurance. Guarded trips
// 1..2 and overflow handled per-node (31%/1%/rare).
template<bool OUT_F16>
__global__ __launch_bounds__(256) void aggregate_kernel(
        const _Float16* __restrict__ h, const float* __restrict__ hs,
        const float* __restrict__ hd, const int* __restrict__ cnt,
        const int* __restrict__ csr, const int* __restrict__ ovf_n,
        const int* __restrict__ ovf, const float* __restrict__ bias,
        float* __restrict__ outf, _Float16* __restrict__ outb, int n) {
    int nodeA = (blockIdx.x * 4 + (threadIdx.x >> 6)) * 2;
    if (nodeA >= n) return;
    int nodeB = nodeA + 1;
    bool hasB = nodeB < n;
    int nBs = hasB ? nodeB : nodeA;       // safe id for B-side loads
    int lane = threadIdx.x & 63;
    int grp = lane >> 4;
    int gl = lane & 15;
    const int baseA = nodeA * SLOTS;
    const int baseB = nBs * SLOTS;
    const uint* hp = (const uint*)h;   // 2 f16 per uint, row stride 64 uints

    // --- speculative trip 0 for BOTH nodes: everything below issues before cnt returns ---
    int degA = cnt[nodeA];
    int degB = cnt[nBs];
    float hdA = hd[nodeA];
    float hdB = hd[nBs];
    int jb = grp * 2;
    int cA0 = csr[baseA + jb];
    int cA1 = csr[baseA + jb + 1];
    int cB0 = csr[baseB + jb];
    int cB1 = csr[baseB + jb + 1];
    int sA0 = ((uint)cA0 < (uint)n) ? cA0 : nodeA;   // safety clamp (cheap)
    int sA1 = ((uint)cA1 < (uint)n) ? cA1 : nodeA;
    int sB0 = ((uint)cB0 < (uint)n) ? cB0 : nBs;
    int sB1 = ((uint)cB1 < (uint)n) ? cB1 : nBs;
    uint4 rA0 = *(const uint4*)(hp + ((size_t)sA0 << 6) + (gl << 2));
    uint4 rA1 = *(const uint4*)(hp + ((size_t)sA1 << 6) + (gl << 2));
    uint4 rB0 = *(const uint4*)(hp + ((size_t)sB0 << 6) + (gl << 2));
    uint4 rB1 = *(const uint4*)(hp + ((size_t)sB1 << 6) + (gl << 2));
    float eA0 = hs[sA0] + hdA;
    float eA1 = hs[sA1] + hdA;
    float eB0 = hs[sB0] + hdB;
    float eB1 = hs[sB1] + hdB;

    float accA[8] = {0.f, 0.f, 0.f, 0.f, 0.f, 0.f, 0.f, 0.f};
    float accB[8] = {0.f, 0.f, 0.f, 0.f, 0.f, 0.f, 0.f, 0.f};
    float zA = 0.f, zB = 0.f;

    int mindA = degA < SLOTS ? degA : SLOTS;
    int mindB = degB < SLOTS ? degB : SLOTS;
    eA0 = eA0 > 0.f ? eA0 : NEG_SLOPE * eA0;
    eA1 = eA1 > 0.f ? eA1 : NEG_SLOPE * eA1;
    eB0 = eB0 > 0.f ? eB0 : NEG_SLOPE * eB0;
    eB1 = eB1 > 0.f ? eB1 : NEG_SLOPE * eB1;
    float wA0 = (jb < mindA) ? __expf(eA0) : 0.f;
    float wA1 = (jb + 1 < mindA) ? __expf(eA1) : 0.f;
    float wB0 = (jb < mindB) ? __expf(eB0) : 0.f;
    float wB1 = (jb + 1 < mindB) ? __expf(eB1) : 0.f;
    zA += wA0 + wA1;
    zB += wB0 + wB1;
    acc_pair(accA, rA0, rA1, wA0, wA1);
    acc_pair(accB, rB0, rB1, wB0, wB1);

    // --- guarded trips 1..nt-1, per node (31% take trip 1, ~1% trip 2) ---
    int ntA = (mindA + 7) >> 3;
    for (int u = 1; u < ntA; ++u) {
        int i0 = u * 8 + jb;
        bool a0 = i0 < mindA;
        bool a1 = i0 + 1 < mindA;
        int t0 = a0 ? csr[baseA + i0] : nodeA;
        int t1 = a1 ? csr[baseA + i0 + 1] : nodeA;
        uint4 qA = *(const uint4*)(hp + ((size_t)t0 << 6) + (gl << 2));
        uint4 qB = *(const uint4*)(hp + ((size_t)t1 << 6) + (gl << 2));
        float f0 = hs[t0] + hdA;
        f0 = f0 > 0.f ? f0 : NEG_SLOPE * f0;
        float f1 = hs[t1] + hdA;
        f1 = f1 > 0.f ? f1 : NEG_SLOPE * f1;
        float v0 = a0 ? __expf(f0) : 0.f;
        float v1 = a1 ? __expf(f1) : 0.f;
        zA += v0 + v1;
        acc_pair(accA, qA, qB, v0, v1);
    }
    int ntB = (mindB + 7) >> 3;
    for (int u = 1; u < ntB; ++u) {
        int i0 = u * 8 + jb;
        bool a0 = i0 < mindB;
        bool a1 = i0 + 1 < mindB;
        int t0 = a0 ? csr[baseB + i0] : nBs;
        int t1 = a1 ? csr[baseB + i0 + 1] : nBs;
        uint4 qA = *(const uint4*)(hp + ((size_t)t0 << 6) + (gl << 2));
        uint4 qB = *(const uint4*)(hp + ((size_t)t1 << 6) + (gl << 2));
        float f0 = hs[t0] + hdB;
        f0 = f0 > 0.f ? f0 : NEG_SLOPE * f0;
        float f1 = hs[t1] + hdB;
        f1 = f1 > 0.f ? f1 : NEG_SLOPE * f1;
        float v0 = a0 ? __expf(f0) : 0.f;
        float v1 = a1 ? __expf(f1) : 0.f;
        zB += v0 + v1;
        acc_pair(accB, qA, qB, v0, v1);
    }

    // rare: overflow list scan, per node
    if (degA > SLOTS || degB > SLOTS) {
        int m = *ovf_n;
        if (m > OVF_CAP) m = OVF_CAP;
        for (int i = 0; i < m; ++i) {
            int od = ovf[2 * i];
            if (od == nodeA || (hasB && od == nodeB)) {
                bool isA = (od == nodeA);
                int os = ovf[2 * i + 1];
                float e = hs[os] + (isA ? hdA : hdB);
                e = e > 0.f ? e : NEG_SLOPE * e;
                float wv = __expf(e);
                if (grp == 0) {
                    uint4 rr = *(const uint4*)(hp + ((size_t)os << 6) + (gl << 2));
                    float* ac = isA ? accA : accB;
                    ac[0] = fmaf(wv, lo_f(rr.x), ac[0]); ac[1] = fmaf(wv, hi_f(rr.x), ac[1]);
                    ac[2] = fmaf(wv, lo_f(rr.y), ac[2]); ac[3] = fmaf(wv, hi_f(rr.y), ac[3]);
                    ac[4] = fmaf(wv, lo_f(rr.z), ac[4]); ac[5] = fmaf(wv, hi_f(rr.z), ac[5]);
                    ac[6] = fmaf(wv, lo_f(rr.w), ac[6]); ac[7] = fmaf(wv, hi_f(rr.w), ac[7]);
                    if (isA) zA += wv; else zB += wv;
                }
            }
        }
    }

    // combine the 4 slot groups -> lanes 0..15 hold both full rows
    #pragma unroll
    for (int dlt = 32; dlt >= 16; dlt >>= 1) {
        #pragma unroll
        for (int k = 0; k < 8; ++k) {
            accA[k] += __shfl_down(accA[k], dlt, 64);
            accB[k] += __shfl_down(accB[k], dlt, 64);
        }
        zA += __shfl_down(zA, dlt, 64);
        zB += __shfl_down(zB, dlt, 64);
    }
    if (lane < 16) {
        float4 b0 = *(const float4*)&bias[lane * 8];
        float4 b1 = *(const float4*)&bias[lane * 8 + 4];
        float invA = 1.0f / zA;   // self-loop guarantees z > 0
        float oA[8];
        oA[0] = accA[0] * invA + b0.x; oA[1] = accA[1] * invA + b0.y;
        oA[2] = accA[2] * invA + b0.z; oA[3] = accA[3] * invA + b0.w;
        oA[4] = accA[4] * invA + b1.x; oA[5] = accA[5] * invA + b1.y;
        oA[6] = accA[6] * invA + b1.z; oA[7] = accA[7] * invA + b1.w;
        #pragma unroll
        for (int k = 0; k < 8; ++k) oA[k] = oA[k] > 0.f ? oA[k] : 0.f;
        if constexpr (OUT_F16) {
            alignas(16) _Float16 ob[8];
            #pragma unroll
            for (int k = 0; k < 8; ++k) ob[k] = (_Float16)oA[k];
            *(uint4*)&outb[(size_t)nodeA * D + lane * 8] = *(const uint4*)ob;
        } else {
            float* op = outf + (size_t)nodeA * D + lane * 8;
            *(float4*)op = make_float4(oA[0], oA[1], oA[2], oA[3]);
            *(float4*)(op + 4) = make_float4(oA[4], oA[5], oA[6], oA[7]);
        }
        if (hasB) {
            float invB = 1.0f / zB;
            float oB[8];
            oB[0] = accB[0] * invB + b0.x; oB[1] = accB[1] * invB + b0.y;
            oB[2] = accB[2] * invB + b0.z; oB[3] = accB[3] * invB + b0.w;
            oB[4] = accB[4] * invB + b1.x; oB[5] = accB[5] * invB + b1.y;
            oB[6] = accB[6] * invB + b1.z; oB[7] = accB[7] * invB + b1.w;
            #pragma unroll
            for (int k = 0; k < 8; ++k) oB[k] = oB[k] > 0.f ? oB[k] : 0.f;
            if constexpr (OUT_F16) {
                alignas(16) _Float16 ob[8];
                #pragma unroll
                for (int k = 0; k < 8; ++k) ob[k] = (_Float16)oB[k];
                *(uint4*)&outb[(size_t)nodeB * D + lane * 8] = *(const uint4*)ob;
            } else {
                float* op = outf + (size_t)nodeB * D + lane * 8;
                *(float4*)op = make_float4(oB[0], oB[1], oB[2], oB[3]);
                *(float4*)(op + 4) = make_float4(oB[4], oB[5], oB[6], oB[7]);
            }
        }
    }
}

// ---------------- Orchestration ----------------

extern "C" void kernel_launch(void* const* d_in, const int* in_sizes, int n_in,
                              void* d_out, int out_size, void* d_ws, size_t ws_size,
                              hipStream_t stream) {
    const float* x      = (const float*)d_in[0];
    const int*   ei     = (const int*)d_in[1];
    const float* W1     = (const float*)d_in[2];
    const float* a_src1 = (const float*)d_in[3];
    const float* a_dst1 = (const float*)d_in[4];
    const float* b1     = (const float*)d_in[5];
    const float* W2     = (const float*)d_in[6];
    const float* a_src2 = (const float*)d_in[7];
    const float* a_dst2 = (const float*)d_in[8];
    const float* b2     = (const float*)d_in[9];

    int n    = in_sizes[0] / D;       // 100000
    int e_in = in_sizes[1] / 2;       // 625000
    int e_tot = e_in + n;             // 725000

    // ws: h(f16) | Wt1 | Wt2 | hs | hd | cnt | ovf_n | ovf | csr  (~33 MB)
    _Float16* h   = (_Float16*)d_ws;
    _Float16* Wt1 = h + (size_t)n * D;
    _Float16* Wt2 = Wt1 + D * D;
    float* hs     = (float*)(Wt2 + D * D);
    float* hd     = hs + n;
    int*   cnt    = (int*)(hd + n);
    int*   ovf_n  = cnt + n;
    int*   ovf    = ovf_n + 1;
    int*   csr    = ovf + 2 * OVF_CAP;
    // layer-1 f16 output lives in d_out's first half (dead before agg2's fp32 write)
    _Float16* tb  = (_Float16*)d_out;

    int eb = (e_tot + 2047) / 2048;   // 355 rank blocks (4 edges/thread)
    int nb8 = (n + 7) / 8;            // 12500 (8 nodes per 256-thread block)
    int gb = (n + 127) / 128;         // 782 (eb <= gb required by mega1 mapping)

    prep_kernel<<<128, 256, 0, stream>>>(W1, W2, Wt1, Wt2, cnt, csr, ovf_n, n);
    mega1_kernel<<<gb + eb, 512, 0, stream>>>(x, Wt1, a_src1, a_dst1, h, hs, hd,
                                              ei, cnt, csr, ovf_n, ovf, eb, e_in, n);
    aggregate_kernel<true><<<nb8, 256, 0, stream>>>(h, hs, hd, cnt, csr, ovf_n, ovf,
                                                    b1, nullptr, tb, n);
    gemm2_kernel<<<gb, 512, 0, stream>>>(tb, Wt2, a_src2, a_dst2, h, hs, hd, n);
    aggregate_kernel<false><<<nb8, 256, 0, stream>>>(h, hs, hd, cnt, csr, ovf_n, ovf,
                                                     b2, (float*)d_out, nullptr, n);
}

// Round 13
// 230.160 us; speedup vs baseline: 1.0361x; 1.0110x over previous
//
#include <hip/hip_runtime.h>

#define D 128
#define WS (D + 8)      // LDS row stride in f16: 68 words -> 8-round b128 reads (optimal)
#define NEG_SLOPE 0.2f
#define SLOTS 20        // fixed CSR slots per node; P(deg>20)~3e-5 -> overflow list
#define OVF_CAP 4096

using v8f16 = __attribute__((ext_vector_type(8))) _Float16;
using v2h   = __attribute__((ext_vector_type(2))) _Float16;
using f32x4 = __attribute__((ext_vector_type(4))) float;

// ---------------- prep: zero cnt, init csr slots 0..7 to owning node, convert W1/W2 ----------
// Only the first 8 slots need node-init: the aggregate's speculative trip-0
// reads slots 0..7 unguarded; trips >=1 are cnt-guarded. Rank overwrites
// slots 0..deg-1 deterministically.

__global__ __launch_bounds__(256) void prep_kernel(const float* __restrict__ W1,
        const float* __restrict__ W2, _Float16* __restrict__ Wt1,
        _Float16* __restrict__ Wt2, int* __restrict__ cnt, int* __restrict__ csr,
        int* __restrict__ ovf_n, int n) {
    int t = blockIdx.x * 256 + threadIdx.x;   // 0..32767
    if (t == 0) *ovf_n = 0;
    for (int i = t; i < n; i += 32768) {
        cnt[i] = 0;
        #pragma unroll
        for (int j = 0; j < 8; ++j) csr[i * SLOTS + j] = i;
    }
    int which = t >> 14;
    int idx = t & 16383;
    int k = idx & (D - 1);
    int c = idx >> 7;
    const float* W = which ? W2 : W1;
    _Float16* Wt = which ? Wt2 : Wt1;
    Wt[(size_t)c * D + k] = (_Float16)W[(size_t)k * D + c];
}

// ---------------- GEMM body (R10-proven: LDS-staged W via ds_write, padded, 128-row) --------

// H[n x 128](f16) = X @ W via mfma_f32_16x16x32_f16. 8 waves per block share
// ONE 32KB W stage (128 rows each block). Row stride WS=D+8 gives the proven
// 8-round b128 LDS read pattern (the 800K counted "conflicts" are this
// hardware-floor multi-round pattern -- benign, read-side, R9-verified).
// R2: W must come from LDS. R4: non-swapped MFMA. R6: per-t 32B H stores
// merge in L2. R7+R11: do NOT grow the tile (VGPR blowup / grid
// under-subscription: 782-block 128-row 52-VGPR is the measured optimum).
// R9: keep ds_write staging (global_load_lds drain regresses pure-GEMM).
// Fused epilogue from fp32 accumulators: hs = H·a_src, hd = H·a_dst.
template<bool F16IN>
__device__ __forceinline__ void gemm_body(int bid, const void* __restrict__ Xv,
        const _Float16* __restrict__ Wt, const float* __restrict__ a_src,
        const float* __restrict__ a_dst, _Float16* __restrict__ H,
        float* __restrict__ hs, float* __restrict__ hd, int n,
        _Float16* wl) {
    const int lane = threadIdx.x & 63;
    const int wave = threadIdx.x >> 6;           // 0..7
    const int gl = lane & 15;
    const int q = lane >> 4;
    const int row0 = bid * 128 + wave * 16;

    int arow = row0 + gl;
    if (arow >= n) arow = n - 1;   // clamped load; stores are guarded below

    // A fragments first (independent of LDS staging)
    v8f16 afr[4];
    #pragma unroll
    for (int kc = 0; kc < 4; ++kc) {
        if constexpr (F16IN) {
            const _Float16* Xh = (const _Float16*)Xv;
            afr[kc] = *(const v8f16*)&Xh[(size_t)arow * D + kc * 32 + q * 8];
        } else {
            const float* p = &((const float*)Xv)[(size_t)arow * D + kc * 32 + q * 8];
            float4 x0 = *(const float4*)p;
            float4 x1 = *(const float4*)(p + 4);
            v8f16 t;
            t[0] = (_Float16)x0.x; t[1] = (_Float16)x0.y;
            t[2] = (_Float16)x0.z; t[3] = (_Float16)x0.w;
            t[4] = (_Float16)x1.x; t[5] = (_Float16)x1.y;
            t[6] = (_Float16)x1.z; t[7] = (_Float16)x1.w;
            afr[kc] = t;
        }
    }

    // stage W into LDS: 128 rows x 128 f16, 16 chunks of 8 f16 per row
    for (int i = threadIdx.x; i < D * D / 8; i += 512) {
        int r = i >> 4;
        int c = (i & 15) * 8;
        *(v8f16*)&wl[r * WS + c] = *(const v8f16*)&Wt[r * D + c];
    }
    __syncthreads();

    f32x4 acc[8];
    #pragma unroll
    for (int t = 0; t < 8; ++t) acc[t] = (f32x4){0.f, 0.f, 0.f, 0.f};

    #pragma unroll
    for (int kc = 0; kc < 4; ++kc) {
        #pragma unroll
        for (int t = 0; t < 8; ++t) {
            v8f16 bfr = *(const v8f16*)&wl[(t * 16 + gl) * WS + kc * 32 + q * 8];
            acc[t] = __builtin_amdgcn_mfma_f32_16x16x32_f16(afr[kc], bfr, acc[t], 0, 0, 0);
        }
    }

    float asv[8], adv[8];
    #pragma unroll
    for (int t = 0; t < 8; ++t) { asv[t] = a_src[t * 16 + gl]; adv[t] = a_dst[t * 16 + gl]; }

    // C/D layout: col = t*16 + (lane&15), row = row0 + q*4 + reg
    #pragma unroll
    for (int r = 0; r < 4; ++r) {
        int row = row0 + q * 4 + r;
        bool ok = row < n;
        float ps = 0.f, pd = 0.f;
        #pragma unroll
        for (int t = 0; t < 8; ++t) {
            float v = acc[t][r];
            ps = fmaf(v, asv[t], ps);
            pd = fmaf(v, adv[t], pd);
            if (ok) H[(size_t)row * D + t * 16 + gl] = (_Float16)v;
        }
        #pragma unroll
        for (int dlt = 8; dlt > 0; dlt >>= 1) {
            ps += __shfl_down(ps, dlt, 16);
            pd += __shfl_down(pd, dlt, 16);
        }
        if (ok && gl == 0) { hs[row] = ps; hd[row] = pd; }
    }
}

// ---------------- mega1: GEMM1 interleaved with rank-to-fixed-slot CSR ----------------
// Blocks < 2*eb alternate GEMM/rank; blocks >= 2*eb are GEMM, so both
// populations are co-resident from t=0 (requires eb <= gb: 709 <= 782 ok).
// R10-proven: rank threads handle TWO edges each. R13: the two edges are
// ADJACENT (tid*2, tid*2+1) so each thread's src pair and dst pair load as
// one int2 (8B, coalesced 512B/wave) -- 2 loads instead of 4. R12 lesson:
// do NOT deepen to 4 edges (rank-population balance breaks; 2 is the knee).

__global__ __launch_bounds__(512) void mega1_kernel(
        const float* __restrict__ x, const _Float16* __restrict__ Wt1,
        const float* __restrict__ a_src1, const float* __restrict__ a_dst1,
        _Float16* __restrict__ h, float* __restrict__ hs, float* __restrict__ hd,
        const int* __restrict__ ei, int* __restrict__ cnt, int* __restrict__ csr,
        int* __restrict__ ovf_n, int* __restrict__ ovf,
        int eb, int e_in, int n) {
    __shared__ _Float16 wl[D * WS];
    int b = blockIdx.x;
    int rid;
    if (b < 2 * eb) {
        if ((b & 1) == 0) {
            gemm_body<false>(b >> 1, x, Wt1, a_src1, a_dst1, h, hs, hd, n, wl);
            return;
        }
        rid = b >> 1;
    } else {
        gemm_body<false>(b - eb, x, Wt1, a_src1, a_dst1, h, hs, hd, n, wl);
        return;
    }
    int tot = e_in + n;
    int e0 = rid * 1024 + threadIdx.x * 2;
    int e1 = e0 + 1;
    bool v0 = e0 < tot, v1 = e1 < tot;
    int s0 = 0, d0 = 0, s1 = 0, d1 = 0;
    if (e1 < e_in) {
        // common case: both edges real, one int2 for src pair + one for dst pair
        int2 sp = *(const int2*)&ei[e0];
        int2 dp = *(const int2*)&ei[e_in + e0];
        s0 = sp.x; s1 = sp.y;
        d0 = dp.x; d1 = dp.y;
    } else {
        // boundary (straddles e_in or tot) / self-loop region: scalar fallback
        if (v0) {
            if (e0 < e_in) { s0 = ei[e0]; d0 = ei[e_in + e0]; }
            else           { s0 = e0 - e_in; d0 = s0; }
        }
        if (v1) {
            if (e1 < e_in) { s1 = ei[e1]; d1 = ei[e_in + e1]; }
            else           { s1 = e1 - e_in; d1 = s1; }
        }
    }
    int r0 = v0 ? atomicAdd(&cnt[d0], 1) : 0;
    int r1 = v1 ? atomicAdd(&cnt[d1], 1) : 0;
    if (v0) {
        if (r0 < SLOTS) csr[d0 * SLOTS + r0] = s0;
        else {
            int ix = atomicAdd(ovf_n, 1);
            if (ix < OVF_CAP) { ovf[2 * ix] = d0; ovf[2 * ix + 1] = s0; }
        }
    }
    if (v1) {
        if (r1 < SLOTS) csr[d1 * SLOTS + r1] = s1;
        else {
            int ix = atomicAdd(ovf_n, 1);
            if (ix < OVF_CAP) { ovf[2 * ix] = d1; ovf[2 * ix + 1] = s1; }
        }
    }
}

__global__ __launch_bounds__(512) void gemm2_kernel(
        const _Float16* __restrict__ tb, const _Float16* __restrict__ Wt2,
        const float* __restrict__ a_src2, const float* __restrict__ a_dst2,
        _Float16* __restrict__ h, float* __restrict__ hs, float* __restrict__ hd,
        int n) {
    __shared__ _Float16 wl[D * WS];
    gemm_body<true>(blockIdx.x, tb, Wt2, a_src2, a_dst2, h, hs, hd, n, wl);
}

// ---------------- aggregate (unchanged from R8 -- proven) ----------------

__device__ __forceinline__ v2h pack_lo(uint a, uint b) {
    v2h r;
    r.x = __builtin_bit_cast(_Float16, (unsigned short)(a & 0xffffu));
    r.y = __builtin_bit_cast(_Float16, (unsigned short)(b & 0xffffu));
    return r;
}
__device__ __forceinline__ v2h pack_hi(uint a, uint b) {
    v2h r;
    r.x = __builtin_bit_cast(_Float16, (unsigned short)(a >> 16));
    r.y = __builtin_bit_cast(_Float16, (unsigned short)(b >> 16));
    return r;
}
__device__ __forceinline__ float lo_f(uint a) {
    return (float)__builtin_bit_cast(_Float16, (unsigned short)(a & 0xffffu));
}
__device__ __forceinline__ float hi_f(uint a) {
    return (float)__builtin_bit_cast(_Float16, (unsigned short)(a >> 16));
}

// helper: one fdot2 accumulation round (2 slots' rows into acc)
__device__ __forceinline__ void acc_pair(float* acc, const uint4& rA,
        const uint4& rB, float w0, float w1) {
#if __has_builtin(__builtin_amdgcn_fdot2)
    v2h wp; wp.x = (_Float16)w0; wp.y = (_Float16)w1;
    acc[0] = __builtin_amdgcn_fdot2(pack_lo(rA.x, rB.x), wp, acc[0], false);
    acc[1] = __builtin_amdgcn_fdot2(pack_hi(rA.x, rB.x), wp, acc[1], false);
    acc[2] = __builtin_amdgcn_fdot2(pack_lo(rA.y, rB.y), wp, acc[2], false);
    acc[3] = __builtin_amdgcn_fdot2(pack_hi(rA.y, rB.y), wp, acc[3], false);
    acc[4] = __builtin_amdgcn_fdot2(pack_lo(rA.z, rB.z), wp, acc[4], false);
    acc[5] = __builtin_amdgcn_fdot2(pack_hi(rA.z, rB.z), wp, acc[5], false);
    acc[6] = __builtin_amdgcn_fdot2(pack_lo(rA.w, rB.w), wp, acc[6], false);
    acc[7] = __builtin_amdgcn_fdot2(pack_hi(rA.w, rB.w), wp, acc[7], false);
#else
    acc[0] = fmaf(w0, lo_f(rA.x), acc[0]); acc[1] = fmaf(w0, hi_f(rA.x), acc[1]);
    acc[2] = fmaf(w0, lo_f(rA.y), acc[2]); acc[3] = fmaf(w0, hi_f(rA.y), acc[3]);
    acc[4] = fmaf(w0, lo_f(rA.z), acc[4]); acc[5] = fmaf(w0, hi_f(rA.z), acc[5]);
    acc[6] = fmaf(w0, lo_f(rA.w), acc[6]); acc[7] = fmaf(w0, hi_f(rA.w), acc[7]);
    acc[0] = fmaf(w1, lo_f(rB.x), acc[0]); acc[1] = fmaf(w1, hi_f(rB.x), acc[1]);
    acc[2] = fmaf(w1, lo_f(rB.y), acc[2]); acc[3] = fmaf(w1, hi_f(rB.y), acc[3]);
    acc[4] = fmaf(w1, lo_f(rB.z), acc[4]); acc[5] = fmaf(w1, hi_f(rB.z), acc[5]);
    acc[6] = fmaf(w1, lo_f(rB.w), acc[6]); acc[7] = fmaf(w1, hi_f(rB.w), acc[7]);
#endif
}

// TWO nodes per wave (ILP-stacking), 8 nodes per 256-thread block. Per node,
// group grp (lane>>4) handles slot pairs (8u+2*grp, 8u+2*grp+1). TRIP 0 IS
// SPECULATIVE for BOTH nodes: cnt/hd/csr(0..7) for A and B issue concurrently
// (depend only on node id), then all 4 row-gathers + hs -- ~20 loads in
// flight per wave, 2x the old MLP at the same occupancy (VGPR ~56 < 64 step).
// Validity masks (needing cnt) apply to WEIGHTS only; slots 0..7 >= deg hold
// the node id (prep-initialized), bounds clamp as insurance. Guarded trips
// 1..2 and overflow handled per-node (31%/1%/rare). R12 lesson: 2 nodes is
// the ILP knee -- do not deepen (VGPR cliff at 64).
template<bool OUT_F16>
__global__ __launch_bounds__(256) void aggregate_kernel(
        const _Float16* __restrict__ h, const float* __restrict__ hs,
        const float* __restrict__ hd, const int* __restrict__ cnt,
        const int* __restrict__ csr, const int* __restrict__ ovf_n,
        const int* __restrict__ ovf, const float* __restrict__ bias,
        float* __restrict__ outf, _Float16* __restrict__ outb, int n) {
    int nodeA = (blockIdx.x * 4 + (threadIdx.x >> 6)) * 2;
    if (nodeA >= n) return;
    int nodeB = nodeA + 1;
    bool hasB = nodeB < n;
    int nBs = hasB ? nodeB : nodeA;       // safe id for B-side loads
    int lane = threadIdx.x & 63;
    int grp = lane >> 4;
    int gl = lane & 15;
    const int baseA = nodeA * SLOTS;
    const int baseB = nBs * SLOTS;
    const uint* hp = (const uint*)h;   // 2 f16 per uint, row stride 64 uints

    // --- speculative trip 0 for BOTH nodes: everything below issues before cnt returns ---
    int degA = cnt[nodeA];
    int degB = cnt[nBs];
    float hdA = hd[nodeA];
    float hdB = hd[nBs];
    int jb = grp * 2;
    int cA0 = csr[baseA + jb];
    int cA1 = csr[baseA + jb + 1];
    int cB0 = csr[baseB + jb];
    int cB1 = csr[baseB + jb + 1];
    int sA0 = ((uint)cA0 < (uint)n) ? cA0 : nodeA;   // safety clamp (cheap)
    int sA1 = ((uint)cA1 < (uint)n) ? cA1 : nodeA;
    int sB0 = ((uint)cB0 < (uint)n) ? cB0 : nBs;
    int sB1 = ((uint)cB1 < (uint)n) ? cB1 : nBs;
    uint4 rA0 = *(const uint4*)(hp + ((size_t)sA0 << 6) + (gl << 2));
    uint4 rA1 = *(const uint4*)(hp + ((size_t)sA1 << 6) + (gl << 2));
    uint4 rB0 = *(const uint4*)(hp + ((size_t)sB0 << 6) + (gl << 2));
    uint4 rB1 = *(const uint4*)(hp + ((size_t)sB1 << 6) + (gl << 2));
    float eA0 = hs[sA0] + hdA;
    float eA1 = hs[sA1] + hdA;
    float eB0 = hs[sB0] + hdB;
    float eB1 = hs[sB1] + hdB;

    float accA[8] = {0.f, 0.f, 0.f, 0.f, 0.f, 0.f, 0.f, 0.f};
    float accB[8] = {0.f, 0.f, 0.f, 0.f, 0.f, 0.f, 0.f, 0.f};
    float zA = 0.f, zB = 0.f;

    int mindA = degA < SLOTS ? degA : SLOTS;
    int mindB = degB < SLOTS ? degB : SLOTS;
    eA0 = eA0 > 0.f ? eA0 : NEG_SLOPE * eA0;
    eA1 = eA1 > 0.f ? eA1 : NEG_SLOPE * eA1;
    eB0 = eB0 > 0.f ? eB0 : NEG_SLOPE * eB0;
    eB1 = eB1 > 0.f ? eB1 : NEG_SLOPE * eB1;
    float wA0 = (jb < mindA) ? __expf(eA0) : 0.f;
    float wA1 = (jb + 1 < mindA) ? __expf(eA1) : 0.f;
    float wB0 = (jb < mindB) ? __expf(eB0) : 0.f;
    float wB1 = (jb + 1 < mindB) ? __expf(eB1) : 0.f;
    zA += wA0 + wA1;
    zB += wB0 + wB1;
    acc_pair(accA, rA0, rA1, wA0, wA1);
    acc_pair(accB, rB0, rB1, wB0, wB1);

    // --- guarded trips 1..nt-1, per node (31% take trip 1, ~1% trip 2) ---
    int ntA = (mindA + 7) >> 3;
    for (int u = 1; u < ntA; ++u) {
        int i0 = u * 8 + jb;
        bool a0 = i0 < mindA;
        bool a1 = i0 + 1 < mindA;
        int t0 = a0 ? csr[baseA + i0] : nodeA;
        int t1 = a1 ? csr[baseA + i0 + 1] : nodeA;
        uint4 qA = *(const uint4*)(hp + ((size_t)t0 << 6) + (gl << 2));
        uint4 qB = *(const uint4*)(hp + ((size_t)t1 << 6) + (gl << 2));
        float f0 = hs[t0] + hdA;
        f0 = f0 > 0.f ? f0 : NEG_SLOPE * f0;
        float f1 = hs[t1] + hdA;
        f1 = f1 > 0.f ? f1 : NEG_SLOPE * f1;
        float v0 = a0 ? __expf(f0) : 0.f;
        float v1 = a1 ? __expf(f1) : 0.f;
        zA += v0 + v1;
        acc_pair(accA, qA, qB, v0, v1);
    }
    int ntB = (mindB + 7) >> 3;
    for (int u = 1; u < ntB; ++u) {
        int i0 = u * 8 + jb;
        bool a0 = i0 < mindB;
        bool a1 = i0 + 1 < mindB;
        int t0 = a0 ? csr[baseB + i0] : nBs;
        int t1 = a1 ? csr[baseB + i0 + 1] : nBs;
        uint4 qA = *(const uint4*)(hp + ((size_t)t0 << 6) + (gl << 2));
        uint4 qB = *(const uint4*)(hp + ((size_t)t1 << 6) + (gl << 2));
        float f0 = hs[t0] + hdB;
        f0 = f0 > 0.f ? f0 : NEG_SLOPE * f0;
        float f1 = hs[t1] + hdB;
        f1 = f1 > 0.f ? f1 : NEG_SLOPE * f1;
        float v0 = a0 ? __expf(f0) : 0.f;
        float v1 = a1 ? __expf(f1) : 0.f;
        zB += v0 + v1;
        acc_pair(accB, qA, qB, v0, v1);
    }

    // rare: overflow list scan, per node
    if (degA > SLOTS || degB > SLOTS) {
        int m = *ovf_n;
        if (m > OVF_CAP) m = OVF_CAP;
        for (int i = 0; i < m; ++i) {
            int od = ovf[2 * i];
            if (od == nodeA || (hasB && od == nodeB)) {
                bool isA = (od == nodeA);
                int os = ovf[2 * i + 1];
                float e = hs[os] + (isA ? hdA : hdB);
                e = e > 0.f ? e : NEG_SLOPE * e;
                float wv = __expf(e);
                if (grp == 0) {
                    uint4 rr = *(const uint4*)(hp + ((size_t)os << 6) + (gl << 2));
                    float* ac = isA ? accA : accB;
                    ac[0] = fmaf(wv, lo_f(rr.x), ac[0]); ac[1] = fmaf(wv, hi_f(rr.x), ac[1]);
                    ac[2] = fmaf(wv, lo_f(rr.y), ac[2]); ac[3] = fmaf(wv, hi_f(rr.y), ac[3]);
                    ac[4] = fmaf(wv, lo_f(rr.z), ac[4]); ac[5] = fmaf(wv, hi_f(rr.z), ac[5]);
                    ac[6] = fmaf(wv, lo_f(rr.w), ac[6]); ac[7] = fmaf(wv, hi_f(rr.w), ac[7]);
                    if (isA) zA += wv; else zB += wv;
                }
            }
        }
    }

    // combine the 4 slot groups -> lanes 0..15 hold both full rows
    #pragma unroll
    for (int dlt = 32; dlt >= 16; dlt >>= 1) {
        #pragma unroll
        for (int k = 0; k < 8; ++k) {
            accA[k] += __shfl_down(accA[k], dlt, 64);
            accB[k] += __shfl_down(accB[k], dlt, 64);
        }
        zA += __shfl_down(zA, dlt, 64);
        zB += __shfl_down(zB, dlt, 64);
    }
    if (lane < 16) {
        float4 b0 = *(const float4*)&bias[lane * 8];
        float4 b1 = *(const float4*)&bias[lane * 8 + 4];
        float invA = 1.0f / zA;   // self-loop guarantees z > 0
        float oA[8];
        oA[0] = accA[0] * invA + b0.x; oA[1] = accA[1] * invA + b0.y;
        oA[2] = accA[2] * invA + b0.z; oA[3] = accA[3] * invA + b0.w;
        oA[4] = accA[4] * invA + b1.x; oA[5] = accA[5] * invA + b1.y;
        oA[6] = accA[6] * invA + b1.z; oA[7] = accA[7] * invA + b1.w;
        #pragma unroll
        for (int k = 0; k < 8; ++k) oA[k] = oA[k] > 0.f ? oA[k] : 0.f;
        if constexpr (OUT_F16) {
            alignas(16) _Float16 ob[8];
            #pragma unroll
            for (int k = 0; k < 8; ++k) ob[k] = (_Float16)oA[k];
            *(uint4*)&outb[(size_t)nodeA * D + lane * 8] = *(const uint4*)ob;
        } else {
            float* op = outf + (size_t)nodeA * D + lane * 8;
            *(float4*)op = make_float4(oA[0], oA[1], oA[2], oA[3]);
            *(float4*)(op + 4) = make_float4(oA[4], oA[5], oA[6], oA[7]);
        }
        if (hasB) {
            float invB = 1.0f / zB;
            float oB[8];
            oB[0] = accB[0] * invB + b0.x; oB[1] = accB[1] * invB + b0.y;
            oB[2] = accB[2] * invB + b0.z; oB[3] = accB[3] * invB + b0.w;
            oB[4] = accB[4] * invB + b1.x; oB[5] = accB[5] * invB + b1.y;
            oB[6] = accB[6] * invB + b1.z; oB[7] = accB[7] * invB + b1.w;
            #pragma unroll
            for (int k = 0; k < 8; ++k) oB[k] = oB[k] > 0.f ? oB[k] : 0.f;
            if constexpr (OUT_F16) {
                alignas(16) _Float16 ob[8];
                #pragma unroll
                for (int k = 0; k < 8; ++k) ob[k] = (_Float16)oB[k];
                *(uint4*)&outb[(size_t)nodeB * D + lane * 8] = *(const uint4*)ob;
            } else {
                float* op = outf + (size_t)nodeB * D + lane * 8;
                *(float4*)op = make_float4(oB[0], oB[1], oB[2], oB[3]);
                *(float4*)(op + 4) = make_float4(oB[4], oB[5], oB[6], oB[7]);
            }
        }
    }
}

// ---------------- Orchestration ----------------

extern "C" void kernel_launch(void* const* d_in, const int* in_sizes, int n_in,
                              void* d_out, int out_size, void* d_ws, size_t ws_size,
                              hipStream_t stream) {
    const float* x      = (const float*)d_in[0];
    const int*   ei     = (const int*)d_in[1];
    const float* W1     = (const float*)d_in[2];
    const float* a_src1 = (const float*)d_in[3];
    const float* a_dst1 = (const float*)d_in[4];
    const float* b1     = (const float*)d_in[5];
    const float* W2     = (const float*)d_in[6];
    const float* a_src2 = (const float*)d_in[7];
    const float* a_dst2 = (const float*)d_in[8];
    const float* b2     = (const float*)d_in[9];

    int n    = in_sizes[0] / D;       // 100000
    int e_in = in_sizes[1] / 2;       // 625000
    int e_tot = e_in + n;             // 725000

    // ws: h(f16) | Wt1 | Wt2 | hs | hd | cnt | ovf_n | ovf | csr  (~33 MB)
    _Float16* h   = (_Float16*)d_ws;
    _Float16* Wt1 = h + (size_t)n * D;
    _Float16* Wt2 = Wt1 + D * D;
    float* hs     = (float*)(Wt2 + D * D);
    float* hd     = hs + n;
    int*   cnt    = (int*)(hd + n);
    int*   ovf_n  = cnt + n;
    int*   ovf    = ovf_n + 1;
    int*   csr    = ovf + 2 * OVF_CAP;
    // layer-1 f16 output lives in d_out's first half (dead before agg2's fp32 write)
    _Float16* tb  = (_Float16*)d_out;

    int eb = (e_tot + 1023) / 1024;   // 709 rank blocks (2 adjacent edges/thread)
    int nb8 = (n + 7) / 8;            // 12500 (8 nodes per 256-thread block)
    int gb = (n + 127) / 128;         // 782 (eb <= gb required by mega1 mapping)

    prep_kernel<<<128, 256, 0, stream>>>(W1, W2, Wt1, Wt2, cnt, csr, ovf_n, n);
    mega1_kernel<<<gb + eb, 512, 0, stream>>>(x, Wt1, a_src1, a_dst1, h, hs, hd,
                                              ei, cnt, csr, ovf_n, ovf, eb, e_in, n);
    aggregate_kernel<true><<<nb8, 256, 0, stream>>>(h, hs, hd, cnt, csr, ovf_n, ovf,
                                                    b1, nullptr, tb, n);
    gemm2_kernel<<<gb, 512, 0, stream>>>(tb, Wt2, a_src2, a_dst2, h, hs, hd, n);
    aggregate_kernel<false><<<nb8, 256, 0, stream>>>(h, hs, hd, cnt, csr, ovf_n, ovf,
                                                     b2, (float*)d_out, nullptr, n);
}

// Round 14
// 228.367 us; speedup vs baseline: 1.0442x; 1.0079x over previous
//
#include <hip/hip_runtime.h>

#define D 128
#define WS (D + 8)      // LDS row stride in f16: 68 words -> 8-round b128 reads (optimal)
#define NEG_SLOPE 0.2f
#define SLOTS 20        // fixed CSR slots per node; P(deg>20)~3e-5 -> overflow list
#define OVF_CAP 4096

using v8f16 = __attribute__((ext_vector_type(8))) _Float16;
using v2h   = __attribute__((ext_vector_type(2))) _Float16;
using f32x4 = __attribute__((ext_vector_type(4))) float;

// ---------------- prep: zero cnt, init csr slots 0..7 to owning node, convert W1/W2 ----------
// Only the first 8 slots need node-init: the aggregate's speculative trip-0
// reads slots 0..7 unguarded; trips >=1 are cnt-guarded. Rank overwrites
// slots 0..deg-1 deterministically.

__global__ __launch_bounds__(256) void prep_kernel(const float* __restrict__ W1,
        const float* __restrict__ W2, _Float16* __restrict__ Wt1,
        _Float16* __restrict__ Wt2, int* __restrict__ cnt, int* __restrict__ csr,
        int* __restrict__ ovf_n, int n) {
    int t = blockIdx.x * 256 + threadIdx.x;   // 0..32767
    if (t == 0) *ovf_n = 0;
    for (int i = t; i < n; i += 32768) {
        cnt[i] = 0;
        #pragma unroll
        for (int j = 0; j < 8; ++j) csr[i * SLOTS + j] = i;
    }
    int which = t >> 14;
    int idx = t & 16383;
    int k = idx & (D - 1);
    int c = idx >> 7;
    const float* W = which ? W2 : W1;
    _Float16* Wt = which ? Wt2 : Wt1;
    Wt[(size_t)c * D + k] = (_Float16)W[(size_t)k * D + c];
}

// ---------------- GEMM body (R10-proven: LDS-staged W via ds_write, padded, 128-row) --------

// H[n x 128](f16) = X @ W via mfma_f32_16x16x32_f16. 8 waves per block share
// ONE 32KB W stage (128 rows each block). Row stride WS=D+8 gives the proven
// 8-round b128 LDS read pattern (the 800K counted "conflicts" are this
// hardware-floor multi-round pattern -- benign, read-side, R9-verified).
// R2: W must come from LDS. R4: non-swapped MFMA. R6: per-t 32B H stores
// merge in L2. R7+R11: do NOT grow the tile (VGPR blowup / grid
// under-subscription: 782-block 128-row 52-VGPR is the measured optimum).
// R9: keep ds_write staging (global_load_lds drain regresses pure-GEMM).
// Fused epilogue from fp32 accumulators: hs = H·a_src, hd = H·a_dst.
template<bool F16IN>
__device__ __forceinline__ void gemm_body(int bid, const void* __restrict__ Xv,
        const _Float16* __restrict__ Wt, const float* __restrict__ a_src,
        const float* __restrict__ a_dst, _Float16* __restrict__ H,
        float* __restrict__ hs, float* __restrict__ hd, int n,
        _Float16* wl) {
    const int lane = threadIdx.x & 63;
    const int wave = threadIdx.x >> 6;           // 0..7
    const int gl = lane & 15;
    const int q = lane >> 4;
    const int row0 = bid * 128 + wave * 16;

    int arow = row0 + gl;
    if (arow >= n) arow = n - 1;   // clamped load; stores are guarded below

    // A fragments first (independent of LDS staging)
    v8f16 afr[4];
    #pragma unroll
    for (int kc = 0; kc < 4; ++kc) {
        if constexpr (F16IN) {
            const _Float16* Xh = (const _Float16*)Xv;
            afr[kc] = *(const v8f16*)&Xh[(size_t)arow * D + kc * 32 + q * 8];
        } else {
            const float* p = &((const float*)Xv)[(size_t)arow * D + kc * 32 + q * 8];
            float4 x0 = *(const float4*)p;
            float4 x1 = *(const float4*)(p + 4);
            v8f16 t;
            t[0] = (_Float16)x0.x; t[1] = (_Float16)x0.y;
            t[2] = (_Float16)x0.z; t[3] = (_Float16)x0.w;
            t[4] = (_Float16)x1.x; t[5] = (_Float16)x1.y;
            t[6] = (_Float16)x1.z; t[7] = (_Float16)x1.w;
            afr[kc] = t;
        }
    }

    // stage W into LDS: 128 rows x 128 f16, 16 chunks of 8 f16 per row
    for (int i = threadIdx.x; i < D * D / 8; i += 512) {
        int r = i >> 4;
        int c = (i & 15) * 8;
        *(v8f16*)&wl[r * WS + c] = *(const v8f16*)&Wt[r * D + c];
    }
    __syncthreads();

    f32x4 acc[8];
    #pragma unroll
    for (int t = 0; t < 8; ++t) acc[t] = (f32x4){0.f, 0.f, 0.f, 0.f};

    #pragma unroll
    for (int kc = 0; kc < 4; ++kc) {
        #pragma unroll
        for (int t = 0; t < 8; ++t) {
            v8f16 bfr = *(const v8f16*)&wl[(t * 16 + gl) * WS + kc * 32 + q * 8];
            acc[t] = __builtin_amdgcn_mfma_f32_16x16x32_f16(afr[kc], bfr, acc[t], 0, 0, 0);
        }
    }

    float asv[8], adv[8];
    #pragma unroll
    for (int t = 0; t < 8; ++t) { asv[t] = a_src[t * 16 + gl]; adv[t] = a_dst[t * 16 + gl]; }

    // C/D layout: col = t*16 + (lane&15), row = row0 + q*4 + reg
    #pragma unroll
    for (int r = 0; r < 4; ++r) {
        int row = row0 + q * 4 + r;
        bool ok = row < n;
        float ps = 0.f, pd = 0.f;
        #pragma unroll
        for (int t = 0; t < 8; ++t) {
            float v = acc[t][r];
            ps = fmaf(v, asv[t], ps);
            pd = fmaf(v, adv[t], pd);
            if (ok) H[(size_t)row * D + t * 16 + gl] = (_Float16)v;
        }
        #pragma unroll
        for (int dlt = 8; dlt > 0; dlt >>= 1) {
            ps += __shfl_down(ps, dlt, 16);
            pd += __shfl_down(pd, dlt, 16);
        }
        if (ok && gl == 0) { hs[row] = ps; hd[row] = pd; }
    }
}

// ---------------- mega1: GEMM1 interleaved with rank-to-fixed-slot CSR ----------------
// Blocks < 2*eb alternate GEMM/rank; blocks >= 2*eb are GEMM, so both
// populations are co-resident from t=0 (requires eb <= gb: 709 <= 782 ok).
// R10-proven: rank threads handle TWO edges each (R8 ILP recipe on the
// scatter): both ei loads, both atomics, both csr stores issue independently.
// R12 lesson: do NOT deepen to 4 edges (population balance breaks; 2 = knee).
// R13 lesson: int2 edge-pair vectorization is neutral -- keep strided form.

__global__ __launch_bounds__(512) void mega1_kernel(
        const float* __restrict__ x, const _Float16* __restrict__ Wt1,
        const float* __restrict__ a_src1, const float* __restrict__ a_dst1,
        _Float16* __restrict__ h, float* __restrict__ hs, float* __restrict__ hd,
        const int* __restrict__ ei, int* __restrict__ cnt, int* __restrict__ csr,
        int* __restrict__ ovf_n, int* __restrict__ ovf,
        int eb, int e_in, int n) {
    __shared__ _Float16 wl[D * WS];
    int b = blockIdx.x;
    int rid;
    if (b < 2 * eb) {
        if ((b & 1) == 0) {
            gemm_body<false>(b >> 1, x, Wt1, a_src1, a_dst1, h, hs, hd, n, wl);
            return;
        }
        rid = b >> 1;
    } else {
        gemm_body<false>(b - eb, x, Wt1, a_src1, a_dst1, h, hs, hd, n, wl);
        return;
    }
    int tot = e_in + n;
    int e0 = rid * 1024 + threadIdx.x;
    int e1 = e0 + 512;
    bool v0 = e0 < tot, v1 = e1 < tot;
    int s0 = 0, d0 = 0, s1 = 0, d1 = 0;
    if (v0) {
        if (e0 < e_in) { s0 = ei[e0]; d0 = ei[e_in + e0]; }
        else           { s0 = e0 - e_in; d0 = s0; }
    }
    if (v1) {
        if (e1 < e_in) { s1 = ei[e1]; d1 = ei[e_in + e1]; }
        else           { s1 = e1 - e_in; d1 = s1; }
    }
    int r0 = v0 ? atomicAdd(&cnt[d0], 1) : 0;
    int r1 = v1 ? atomicAdd(&cnt[d1], 1) : 0;
    if (v0) {
        if (r0 < SLOTS) csr[d0 * SLOTS + r0] = s0;
        else {
            int ix = atomicAdd(ovf_n, 1);
            if (ix < OVF_CAP) { ovf[2 * ix] = d0; ovf[2 * ix + 1] = s0; }
        }
    }
    if (v1) {
        if (r1 < SLOTS) csr[d1 * SLOTS + r1] = s1;
        else {
            int ix = atomicAdd(ovf_n, 1);
            if (ix < OVF_CAP) { ovf[2 * ix] = d1; ovf[2 * ix + 1] = s1; }
        }
    }
}

__global__ __launch_bounds__(512) void gemm2_kernel(
        const _Float16* __restrict__ tb, const _Float16* __restrict__ Wt2,
        const float* __restrict__ a_src2, const float* __restrict__ a_dst2,
        _Float16* __restrict__ h, float* __restrict__ hs, float* __restrict__ hd,
        int n) {
    __shared__ _Float16 wl[D * WS];
    gemm_body<true>(blockIdx.x, tb, Wt2, a_src2, a_dst2, h, hs, hd, n, wl);
}

// ---------------- aggregate (R8-proven) ----------------

__device__ __forceinline__ v2h pack_lo(uint a, uint b) {
    v2h r;
    r.x = __builtin_bit_cast(_Float16, (unsigned short)(a & 0xffffu));
    r.y = __builtin_bit_cast(_Float16, (unsigned short)(b & 0xffffu));
    return r;
}
__device__ __forceinline__ v2h pack_hi(uint a, uint b) {
    v2h r;
    r.x = __builtin_bit_cast(_Float16, (unsigned short)(a >> 16));
    r.y = __builtin_bit_cast(_Float16, (unsigned short)(b >> 16));
    return r;
}
__device__ __forceinline__ float lo_f(uint a) {
    return (float)__builtin_bit_cast(_Float16, (unsigned short)(a & 0xffffu));
}
__device__ __forceinline__ float hi_f(uint a) {
    return (float)__builtin_bit_cast(_Float16, (unsigned short)(a >> 16));
}

// helper: one fdot2 accumulation round (2 slots' rows into acc)
__device__ __forceinline__ void acc_pair(float* acc, const uint4& rA,
        const uint4& rB, float w0, float w1) {
#if __has_builtin(__builtin_amdgcn_fdot2)
    v2h wp; wp.x = (_Float16)w0; wp.y = (_Float16)w1;
    acc[0] = __builtin_amdgcn_fdot2(pack_lo(rA.x, rB.x), wp, acc[0], false);
    acc[1] = __builtin_amdgcn_fdot2(pack_hi(rA.x, rB.x), wp, acc[1], false);
    acc[2] = __builtin_amdgcn_fdot2(pack_lo(rA.y, rB.y), wp, acc[2], false);
    acc[3] = __builtin_amdgcn_fdot2(pack_hi(rA.y, rB.y), wp, acc[3], false);
    acc[4] = __builtin_amdgcn_fdot2(pack_lo(rA.z, rB.z), wp, acc[4], false);
    acc[5] = __builtin_amdgcn_fdot2(pack_hi(rA.z, rB.z), wp, acc[5], false);
    acc[6] = __builtin_amdgcn_fdot2(pack_lo(rA.w, rB.w), wp, acc[6], false);
    acc[7] = __builtin_amdgcn_fdot2(pack_hi(rA.w, rB.w), wp, acc[7], false);
#else
    acc[0] = fmaf(w0, lo_f(rA.x), acc[0]); acc[1] = fmaf(w0, hi_f(rA.x), acc[1]);
    acc[2] = fmaf(w0, lo_f(rA.y), acc[2]); acc[3] = fmaf(w0, hi_f(rA.y), acc[3]);
    acc[4] = fmaf(w0, lo_f(rA.z), acc[4]); acc[5] = fmaf(w0, hi_f(rA.z), acc[5]);
    acc[6] = fmaf(w0, lo_f(rA.w), acc[6]); acc[7] = fmaf(w0, hi_f(rA.w), acc[7]);
    acc[0] = fmaf(w1, lo_f(rB.x), acc[0]); acc[1] = fmaf(w1, hi_f(rB.x), acc[1]);
    acc[2] = fmaf(w1, lo_f(rB.y), acc[2]); acc[3] = fmaf(w1, hi_f(rB.y), acc[3]);
    acc[4] = fmaf(w1, lo_f(rB.z), acc[4]); acc[5] = fmaf(w1, hi_f(rB.z), acc[5]);
    acc[6] = fmaf(w1, lo_f(rB.w), acc[6]); acc[7] = fmaf(w1, hi_f(rB.w), acc[7]);
#endif
}

// TWO nodes per wave (ILP-stacking), 8 nodes per 256-thread block. Per node,
// group grp (lane>>4) handles slot pairs (8u+2*grp, 8u+2*grp+1). TRIP 0 IS
// SPECULATIVE for BOTH nodes: cnt/hd/csr(0..7) for A and B issue concurrently
// (depend only on node id), then all 4 row-gathers + hs -- ~20 loads in
// flight per wave, 2x the old MLP at the same occupancy (VGPR ~56 < 64 step).
// Validity masks (needing cnt) apply to WEIGHTS only; slots 0..7 >= deg hold
// the node id (prep-initialized), bounds clamp as insurance. Guarded trips
// 1..2 and overflow handled per-node (31%/1%/rare). R12 lesson: 2 nodes is
// the ILP knee -- do not deepen (VGPR cliff at 64).
template<bool OUT_F16>
__global__ __launch_bounds__(256) void aggregate_kernel(
        const _Float16* __restrict__ h, const float* __restrict__ hs,
        const float* __restrict__ hd, const int* __restrict__ cnt,
        const int* __restrict__ csr, const int* __restrict__ ovf_n,
        const int* __restrict__ ovf, const float* __restrict__ bias,
        float* __restrict__ outf, _Float16* __restrict__ outb, int n) {
    int nodeA = (blockIdx.x * 4 + (threadIdx.x >> 6)) * 2;
    if (nodeA >= n) return;
    int nodeB = nodeA + 1;
    bool hasB = nodeB < n;
    int nBs = hasB ? nodeB : nodeA;       // safe id for B-side loads
    int lane = threadIdx.x & 63;
    int grp = lane >> 4;
    int gl = lane & 15;
    const int baseA = nodeA * SLOTS;
    const int baseB = nBs * SLOTS;
    const uint* hp = (const uint*)h;   // 2 f16 per uint, row stride 64 uints

    // --- speculative trip 0 for BOTH nodes: everything below issues before cnt returns ---
    int degA = cnt[nodeA];
    int degB = cnt[nBs];
    float hdA = hd[nodeA];
    float hdB = hd[nBs];
    int jb = grp * 2;
    int cA0 = csr[baseA + jb];
    int cA1 = csr[baseA + jb + 1];
    int cB0 = csr[baseB + jb];
    int cB1 = csr[baseB + jb + 1];
    int sA0 = ((uint)cA0 < (uint)n) ? cA0 : nodeA;   // safety clamp (cheap)
    int sA1 = ((uint)cA1 < (uint)n) ? cA1 : nodeA;
    int sB0 = ((uint)cB0 < (uint)n) ? cB0 : nBs;
    int sB1 = ((uint)cB1 < (uint)n) ? cB1 : nBs;
    uint4 rA0 = *(const uint4*)(hp + ((size_t)sA0 << 6) + (gl << 2));
    uint4 rA1 = *(const uint4*)(hp + ((size_t)sA1 << 6) + (gl << 2));
    uint4 rB0 = *(const uint4*)(hp + ((size_t)sB0 << 6) + (gl << 2));
    uint4 rB1 = *(const uint4*)(hp + ((size_t)sB1 << 6) + (gl << 2));
    float eA0 = hs[sA0] + hdA;
    float eA1 = hs[sA1] + hdA;
    float eB0 = hs[sB0] + hdB;
    float eB1 = hs[sB1] + hdB;

    float accA[8] = {0.f, 0.f, 0.f, 0.f, 0.f, 0.f, 0.f, 0.f};
    float accB[8] = {0.f, 0.f, 0.f, 0.f, 0.f, 0.f, 0.f, 0.f};
    float zA = 0.f, zB = 0.f;

    int mindA = degA < SLOTS ? degA : SLOTS;
    int mindB = degB < SLOTS ? degB : SLOTS;
    eA0 = eA0 > 0.f ? eA0 : NEG_SLOPE * eA0;
    eA1 = eA1 > 0.f ? eA1 : NEG_SLOPE * eA1;
    eB0 = eB0 > 0.f ? eB0 : NEG_SLOPE * eB0;
    eB1 = eB1 > 0.f ? eB1 : NEG_SLOPE * eB1;
    float wA0 = (jb < mindA) ? __expf(eA0) : 0.f;
    float wA1 = (jb + 1 < mindA) ? __expf(eA1) : 0.f;
    float wB0 = (jb < mindB) ? __expf(eB0) : 0.f;
    float wB1 = (jb + 1 < mindB) ? __expf(eB1) : 0.f;
    zA += wA0 + wA1;
    zB += wB0 + wB1;
    acc_pair(accA, rA0, rA1, wA0, wA1);
    acc_pair(accB, rB0, rB1, wB0, wB1);

    // --- guarded trips 1..nt-1, per node (31% take trip 1, ~1% trip 2) ---
    int ntA = (mindA + 7) >> 3;
    for (int u = 1; u < ntA; ++u) {
        int i0 = u * 8 + jb;
        bool a0 = i0 < mindA;
        bool a1 = i0 + 1 < mindA;
        int t0 = a0 ? csr[baseA + i0] : nodeA;
        int t1 = a1 ? csr[baseA + i0 + 1] : nodeA;
        uint4 qA = *(const uint4*)(hp + ((size_t)t0 << 6) + (gl << 2));
        uint4 qB = *(const uint4*)(hp + ((size_t)t1 << 6) + (gl << 2));
        float f0 = hs[t0] + hdA;
        f0 = f0 > 0.f ? f0 : NEG_SLOPE * f0;
        float f1 = hs[t1] + hdA;
        f1 = f1 > 0.f ? f1 : NEG_SLOPE * f1;
        float v0 = a0 ? __expf(f0) : 0.f;
        float v1 = a1 ? __expf(f1) : 0.f;
        zA += v0 + v1;
        acc_pair(accA, qA, qB, v0, v1);
    }
    int ntB = (mindB + 7) >> 3;
    for (int u = 1; u < ntB; ++u) {
        int i0 = u * 8 + jb;
        bool a0 = i0 < mindB;
        bool a1 = i0 + 1 < mindB;
        int t0 = a0 ? csr[baseB + i0] : nBs;
        int t1 = a1 ? csr[baseB + i0 + 1] : nBs;
        uint4 qA = *(const uint4*)(hp + ((size_t)t0 << 6) + (gl << 2));
        uint4 qB = *(const uint4*)(hp + ((size_t)t1 << 6) + (gl << 2));
        float f0 = hs[t0] + hdB;
        f0 = f0 > 0.f ? f0 : NEG_SLOPE * f0;
        float f1 = hs[t1] + hdB;
        f1 = f1 > 0.f ? f1 : NEG_SLOPE * f1;
        float v0 = a0 ? __expf(f0) : 0.f;
        float v1 = a1 ? __expf(f1) : 0.f;
        zB += v0 + v1;
        acc_pair(accB, qA, qB, v0, v1);
    }

    // rare: overflow list scan, per node
    if (degA > SLOTS || degB > SLOTS) {
        int m = *ovf_n;
        if (m > OVF_CAP) m = OVF_CAP;
        for (int i = 0; i < m; ++i) {
            int od = ovf[2 * i];
            if (od == nodeA || (hasB && od == nodeB)) {
                bool isA = (od == nodeA);
                int os = ovf[2 * i + 1];
                float e = hs[os] + (isA ? hdA : hdB);
                e = e > 0.f ? e : NEG_SLOPE * e;
                float wv = __expf(e);
                if (grp == 0) {
                    uint4 rr = *(const uint4*)(hp + ((size_t)os << 6) + (gl << 2));
                    float* ac = isA ? accA : accB;
                    ac[0] = fmaf(wv, lo_f(rr.x), ac[0]); ac[1] = fmaf(wv, hi_f(rr.x), ac[1]);
                    ac[2] = fmaf(wv, lo_f(rr.y), ac[2]); ac[3] = fmaf(wv, hi_f(rr.y), ac[3]);
                    ac[4] = fmaf(wv, lo_f(rr.z), ac[4]); ac[5] = fmaf(wv, hi_f(rr.z), ac[5]);
                    ac[6] = fmaf(wv, lo_f(rr.w), ac[6]); ac[7] = fmaf(wv, hi_f(rr.w), ac[7]);
                    if (isA) zA += wv; else zB += wv;
                }
            }
        }
    }

    // combine the 4 slot groups -> lanes 0..15 hold both full rows
    #pragma unroll
    for (int dlt = 32; dlt >= 16; dlt >>= 1) {
        #pragma unroll
        for (int k = 0; k < 8; ++k) {
            accA[k] += __shfl_down(accA[k], dlt, 64);
            accB[k] += __shfl_down(accB[k], dlt, 64);
        }
        zA += __shfl_down(zA, dlt, 64);
        zB += __shfl_down(zB, dlt, 64);
    }
    if (lane < 16) {
        float4 b0 = *(const float4*)&bias[lane * 8];
        float4 b1 = *(const float4*)&bias[lane * 8 + 4];
        float invA = 1.0f / zA;   // self-loop guarantees z > 0
        float oA[8];
        oA[0] = accA[0] * invA + b0.x; oA[1] = accA[1] * invA + b0.y;
        oA[2] = accA[2] * invA + b0.z; oA[3] = accA[3] * invA + b0.w;
        oA[4] = accA[4] * invA + b1.x; oA[5] = accA[5] * invA + b1.y;
        oA[6] = accA[6] * invA + b1.z; oA[7] = accA[7] * invA + b1.w;
        #pragma unroll
        for (int k = 0; k < 8; ++k) oA[k] = oA[k] > 0.f ? oA[k] : 0.f;
        if constexpr (OUT_F16) {
            alignas(16) _Float16 ob[8];
            #pragma unroll
            for (int k = 0; k < 8; ++k) ob[k] = (_Float16)oA[k];
            *(uint4*)&outb[(size_t)nodeA * D + lane * 8] = *(const uint4*)ob;
        } else {
            float* op = outf + (size_t)nodeA * D + lane * 8;
            *(float4*)op = make_float4(oA[0], oA[1], oA[2], oA[3]);
            *(float4*)(op + 4) = make_float4(oA[4], oA[5], oA[6], oA[7]);
        }
        if (hasB) {
            float invB = 1.0f / zB;
            float oB[8];
            oB[0] = accB[0] * invB + b0.x; oB[1] = accB[1] * invB + b0.y;
            oB[2] = accB[2] * invB + b0.z; oB[3] = accB[3] * invB + b0.w;
            oB[4] = accB[4] * invB + b1.x; oB[5] = accB[5] * invB + b1.y;
            oB[6] = accB[6] * invB + b1.z; oB[7] = accB[7] * invB + b1.w;
            #pragma unroll
            for (int k = 0; k < 8; ++k) oB[k] = oB[k] > 0.f ? oB[k] : 0.f;
            if constexpr (OUT_F16) {
                alignas(16) _Float16 ob[8];
                #pragma unroll
                for (int k = 0; k < 8; ++k) ob[k] = (_Float16)oB[k];
                *(uint4*)&outb[(size_t)nodeB * D + lane * 8] = *(const uint4*)ob;
            } else {
                float* op = outf + (size_t)nodeB * D + lane * 8;
                *(float4*)op = make_float4(oB[0], oB[1], oB[2], oB[3]);
                *(float4*)(op + 4) = make_float4(oB[4], oB[5], oB[6], oB[7]);
            }
        }
    }
}

// ---------------- Orchestration ----------------

extern "C" void kernel_launch(void* const* d_in, const int* in_sizes, int n_in,
                              void* d_out, int out_size, void* d_ws, size_t ws_size,
                              hipStream_t stream) {
    const float* x      = (const float*)d_in[0];
    const int*   ei     = (const int*)d_in[1];
    const float* W1     = (const float*)d_in[2];
    const float* a_src1 = (const float*)d_in[3];
    const float* a_dst1 = (const float*)d_in[4];
    const float* b1     = (const float*)d_in[5];
    const float* W2     = (const float*)d_in[6];
    const float* a_src2 = (const float*)d_in[7];
    const float* a_dst2 = (const float*)d_in[8];
    const float* b2     = (const float*)d_in[9];

    int n    = in_sizes[0] / D;       // 100000
    int e_in = in_sizes[1] / 2;       // 625000
    int e_tot = e_in + n;             // 725000

    // ws: h(f16) | Wt1 | Wt2 | hs | hd | cnt | ovf_n | ovf | csr  (~33 MB)
    _Float16* h   = (_Float16*)d_ws;
    _Float16* Wt1 = h + (size_t)n * D;
    _Float16* Wt2 = Wt1 + D * D;
    float* hs     = (float*)(Wt2 + D * D);
    float* hd     = hs + n;
    int*   cnt    = (int*)(hd + n);
    int*   ovf_n  = cnt + n;
    int*   ovf    = ovf_n + 1;
    int*   csr    = ovf + 2 * OVF_CAP;
    // layer-1 f16 output lives in d_out's first half (dead before agg2's fp32 write)
    _Float16* tb  = (_Float16*)d_out;

    int eb = (e_tot + 1023) / 1024;   // 709 rank blocks (2 edges/thread)
    int nb8 = (n + 7) / 8;            // 12500 (8 nodes per 256-thread block)
    int gb = (n + 127) / 128;         // 782 (eb <= gb required by mega1 mapping)

    prep_kernel<<<128, 256, 0, stream>>>(W1, W2, Wt1, Wt2, cnt, csr, ovf_n, n);
    mega1_kernel<<<gb + eb, 512, 0, stream>>>(x, Wt1, a_src1, a_dst1, h, hs, hd,
                                              ei, cnt, csr, ovf_n, ovf, eb, e_in, n);
    aggregate_kernel<true><<<nb8, 256, 0, stream>>>(h, hs, hd, cnt, csr, ovf_n, ovf,
                                                    b1, nullptr, tb, n);
    gemm2_kernel<<<gb, 512, 0, stream>>>(tb, Wt2, a_src2, a_dst2, h, hs, hd, n);
    aggregate_kernel<false><<<nb8, 256, 0, stream>>>(h, hs, hd, cnt, csr, ovf_n, ovf,
                                                     b2, (float*)d_out, nullptr, n);
}